// Round 5
// baseline (470.758 us; speedup 1.0000x reference)
//
#include <hip/hip_runtime.h>
#include <stdint.h>

// Problem: B=4, S=2048, D_IN=1024, H=1024; fp32 in/out.
// Pipeline: [prep_mask] [split qkv->bf16 hi/lo] [split+transpose W]
//           [proj_qk GEMM split-bf16 -> Qhi/Qlo/Khi/Klo]
//           [proj_v GEMM plain bf16 -> Vt]
//           [scores GEMM split-bf16 *32 + maskbias -> fp32 scores]
//           [softmax in-place -> bf16 P]   [PV GEMM bf16 -> out]
// NOTE (R3): GEMM __launch_bounds__ min-waves stays 2 — 4 blocks/CU blows the
// per-XCD L2 (FETCH 149->223MB, WRITE 99->421MB, MfmaUtil 35->23%).
// R5: GEMM cores use mfma_f32_32x32x16_bf16 (2495 TF µbench vs 2075 for 16x16:
// ~18% fewer MFMA-busy cycles at identical staging traffic).

#define S_LEN 2048
#define BATCH 4
#define DIN   1024
#define HDIM  1024
#define N3H   3072
#define NTOK  8192   // BATCH*S_LEN

typedef unsigned short u16;
typedef __attribute__((ext_vector_type(8))) short bf16x8;
typedef __attribute__((ext_vector_type(4))) float f32x4;
typedef __attribute__((ext_vector_type(16))) float f32x16;
typedef __attribute__((ext_vector_type(4))) unsigned short u16x4;

// ---------- bf16 helpers (bit ops, RN) ----------
__device__ __forceinline__ u16 f2bf(float x) {
  union { float f; unsigned u; } c; c.f = x;
  unsigned r = c.u + 0x7fffu + ((c.u >> 16) & 1u);
  return (u16)(r >> 16);
}
__device__ __forceinline__ float bf2f(u16 h) {
  union { unsigned u; float f; } c; c.u = ((unsigned)h) << 16;
  return c.f;
}

// ---------- async global->LDS, width 16 ----------
__device__ __forceinline__ void gload16(const void* g, void* lds) {
  auto* gp = reinterpret_cast<const __attribute__((address_space(1))) void*>(
      reinterpret_cast<uintptr_t>(g));
  auto* lp = reinterpret_cast<__attribute__((address_space(3))) void*>(
      (unsigned)reinterpret_cast<uintptr_t>(lds));
  __builtin_amdgcn_global_load_lds(gp, lp, 16, 0, 0);
}

// Stage a 128x32 bf16 tile (row-major, row stride ld elems) into LDS (row-major [128][32]).
__device__ __forceinline__ void stage_tile(const u16* __restrict__ g, int ld,
                                           u16* lds, int wave, int lane) {
  const int rlane = lane >> 2;       // 0..15
  const int kofs  = (lane & 3) * 8;  // 0,8,16,24
#pragma unroll
  for (int h = 0; h < 2; ++h) {
    const int instr = wave * 2 + h;  // 0..7
    const u16* gp = g + (size_t)(instr * 16 + rlane) * ld + kofs;
    gload16(gp, (char*)lds + instr * 1024);
  }
}

// 32x32x16 fragment fetch from a [128][32] LDS tile.
// A-operand layout (by analogy with verified 16x16x32): A[m=lane&31][k=(lane>>5)*8+j].
// Wave tile 64x64 at (wm*64, wn*64); sub-tile i/j in {0,1}; k-half kh in {0,1}.
__device__ __forceinline__ bf16x8 frag32(const u16* t, int wq, int sub, int kh,
                                         int lane) {
  const int row = wq * 64 + sub * 32 + (lane & 31);
  const int k   = kh * 16 + (lane >> 5) * 8;
  return *(const bf16x8*)(t + row * 32 + k);
}

// ---------- split-precision gemm_bt core: C(128x128) += (Ah+Al)*(Bh+Bl)^T ----------
// 3 MFMA products (hh, hl, lh); lo*lo dropped (2^-18 rel, negligible).
__device__ __forceinline__ void gemm_core_split(
    const u16* __restrict__ Ah, const u16* __restrict__ Al,
    const u16* __restrict__ Bh, const u16* __restrict__ Bl,
    int lda, int ldb, int K, f32x16 acc[2][2])
{
  __shared__ __align__(16) u16 lds[4 * 4096];  // aH | aL | bH | bL, 8KB each
  u16* aH = lds;          u16* aL = lds + 4096;
  u16* bH = lds + 8192;   u16* bL = lds + 12288;
  const int tid  = threadIdx.x;
  const int wave = tid >> 6, lane = tid & 63;
  const int wm = wave >> 1, wn = wave & 1;

#pragma unroll
  for (int i = 0; i < 2; ++i)
#pragma unroll
    for (int j = 0; j < 2; ++j)
#pragma unroll
      for (int r = 0; r < 16; ++r) acc[i][j][r] = 0.f;

  for (int k0 = 0; k0 < K; k0 += 32) {
    stage_tile(Ah + k0, lda, aH, wave, lane);
    stage_tile(Al + k0, lda, aL, wave, lane);
    stage_tile(Bh + k0, ldb, bH, wave, lane);
    stage_tile(Bl + k0, ldb, bL, wave, lane);
    __syncthreads();   // drains vmcnt (global_load_lds) before LDS reads

#pragma unroll
    for (int kh = 0; kh < 2; ++kh) {
      bf16x8 fah[2], fal[2];
#pragma unroll
      for (int i = 0; i < 2; ++i) {
        fah[i] = frag32(aH, wm, i, kh, lane);
        fal[i] = frag32(aL, wm, i, kh, lane);
      }
#pragma unroll
      for (int j = 0; j < 2; ++j) {
        const bf16x8 fbh = frag32(bH, wn, j, kh, lane);
        const bf16x8 fbl = frag32(bL, wn, j, kh, lane);
#pragma unroll
        for (int i = 0; i < 2; ++i) {
          acc[i][j] = __builtin_amdgcn_mfma_f32_32x32x16_bf16(fah[i], fbh, acc[i][j], 0, 0, 0);
          acc[i][j] = __builtin_amdgcn_mfma_f32_32x32x16_bf16(fah[i], fbl, acc[i][j], 0, 0, 0);
          acc[i][j] = __builtin_amdgcn_mfma_f32_32x32x16_bf16(fal[i], fbh, acc[i][j], 0, 0, 0);
        }
      }
    }
    __syncthreads();   // protect LDS before next stage
  }
}

// ---------- plain bf16 gemm_bt core ----------
__device__ __forceinline__ void gemm_core_plain(
    const u16* __restrict__ A, const u16* __restrict__ B,
    int lda, int ldb, int K, f32x16 acc[2][2])
{
  __shared__ __align__(16) u16 lds[2 * 4096];
  u16* aT = lds; u16* bT = lds + 4096;
  const int tid  = threadIdx.x;
  const int wave = tid >> 6, lane = tid & 63;
  const int wm = wave >> 1, wn = wave & 1;

#pragma unroll
  for (int i = 0; i < 2; ++i)
#pragma unroll
    for (int j = 0; j < 2; ++j)
#pragma unroll
      for (int r = 0; r < 16; ++r) acc[i][j][r] = 0.f;

  for (int k0 = 0; k0 < K; k0 += 32) {
    stage_tile(A + k0, lda, aT, wave, lane);
    stage_tile(B + k0, ldb, bT, wave, lane);
    __syncthreads();
#pragma unroll
    for (int kh = 0; kh < 2; ++kh) {
      bf16x8 fa[2];
#pragma unroll
      for (int i = 0; i < 2; ++i) fa[i] = frag32(aT, wm, i, kh, lane);
#pragma unroll
      for (int j = 0; j < 2; ++j) {
        const bf16x8 fb = frag32(bT, wn, j, kh, lane);
#pragma unroll
        for (int i = 0; i < 2; ++i)
          acc[i][j] = __builtin_amdgcn_mfma_f32_32x32x16_bf16(fa[i], fb, acc[i][j], 0, 0, 0);
      }
    }
    __syncthreads();
  }
}

// C/D layout for 32x32 (HW-verified m74/m101):
//   col = lane&31, row = (reg&3) + 8*(reg>>2) + 4*(lane>>5)
#define ROW32(r, lane) (((r) & 3) + 8 * ((r) >> 2) + 4 * ((lane) >> 5))

// ---------- mask prep: detect bool(1B) vs int32(4B) repr, write additive bias ----------
__global__ void prep_mask_kernel(const unsigned char* __restrict__ m,
                                 float* __restrict__ bias) {
  __shared__ int isBool;
  if (threadIdx.x == 0) isBool = 0;
  __syncthreads();
  for (int i = threadIdx.x; i < NTOK; i += 256)
    if ((i & 3) && m[i]) isBool = 1;   // int32 repr of 0/1 has zero bytes at %4!=0
  __syncthreads();
  const int stride = isBool ? 1 : 4;
  const float ninf = -__builtin_inff();
  for (int i = threadIdx.x; i < NTOK; i += 256)
    bias[i] = m[(size_t)i * stride] ? ninf : 0.f;
}

// ---------- split fp32 -> bf16 hi/lo ----------
__global__ __launch_bounds__(256) void split_f32_kernel(
    const float* __restrict__ x, u16* __restrict__ hi, u16* __restrict__ lo) {
  const int i = (blockIdx.x * 256 + threadIdx.x) * 4;
  const f32x4 v = *(const f32x4*)(x + i);
  u16x4 h, l;
#pragma unroll
  for (int c = 0; c < 4; ++c) {
    h[c] = f2bf(v[c]);
    l[c] = f2bf(v[c] - bf2f(h[c]));
  }
  *(u16x4*)(hi + i) = h;
  *(u16x4*)(lo + i) = l;
}

// ---------- transpose + split W (DINxN3H -> N3HxDIN) ----------
__global__ __launch_bounds__(256) void splitWT_kernel(
    const float* __restrict__ W, u16* __restrict__ whi, u16* __restrict__ wlo) {
  const int o = blockIdx.x * 256 + threadIdx.x;  // o = n*DIN + d
  const int n = o >> 10, d = o & 1023;
  const float v = W[(size_t)d * N3H + n];
  const u16 h = f2bf(v);
  whi[o] = h;
  wlo[o] = f2bf(v - bf2f(h));
}

// ---------- projection GEMM (Q,K thirds): split precision ----------
__global__ __launch_bounds__(256, 2) void proj_qk_kernel(
    const u16* __restrict__ Ahi, const u16* __restrict__ Alo,
    const u16* __restrict__ Whi, const u16* __restrict__ Wlo,
    const float* __restrict__ bias,
    u16* __restrict__ qhi, u16* __restrict__ qlo,
    u16* __restrict__ khi, u16* __restrict__ klo)
{
  const int bx = blockIdx.x, by = blockIdx.y;  // bx over 16 tiles (cols 0..2047)
  f32x16 acc[2][2];
  gemm_core_split(Ahi + (size_t)by * 128 * DIN, Alo + (size_t)by * 128 * DIN,
                  Whi + (size_t)bx * 128 * DIN, Wlo + (size_t)bx * 128 * DIN,
                  DIN, DIN, DIN, acc);
  const int lane = threadIdx.x & 63, wave = threadIdx.x >> 6;
  const int wm = wave >> 1, wn = wave & 1;
#pragma unroll
  for (int i = 0; i < 2; ++i) {
#pragma unroll
    for (int j = 0; j < 2; ++j) {
#pragma unroll
      for (int r = 0; r < 16; ++r) {
        const int row = by * 128 + wm * 64 + i * 32 + ROW32(r, lane);  // token
        const int col = bx * 128 + wn * 64 + j * 32 + (lane & 31);     // 0..2047
        const float v = acc[i][j][r] + bias[col];
        const u16 h = f2bf(v);
        const u16 l = f2bf(v - bf2f(h));
        if (col < HDIM) {                       // Q (block-uniform branch)
          const size_t idx = (size_t)row * HDIM + col;
          qhi[idx] = h; qlo[idx] = l;
        } else {                                // K
          const size_t idx = (size_t)row * HDIM + (col - HDIM);
          khi[idx] = h; klo[idx] = l;
        }
      }
    }
  }
}

// ---------- projection GEMM (V third): plain bf16, writes V transposed ----------
__global__ __launch_bounds__(256, 2) void proj_v_kernel(
    const u16* __restrict__ Ahi, const u16* __restrict__ Whi,
    const float* __restrict__ bias, u16* __restrict__ vt)
{
  const int bx = blockIdx.x, by = blockIdx.y;  // bx over 8 tiles (cols 2048..3071)
  f32x16 acc[2][2];
  gemm_core_plain(Ahi + (size_t)by * 128 * DIN,
                  Whi + (size_t)(2048 + bx * 128) * DIN,
                  DIN, DIN, DIN, acc);
  const int lane = threadIdx.x & 63, wave = threadIdx.x >> 6;
  const int wm = wave >> 1, wn = wave & 1;
#pragma unroll
  for (int i = 0; i < 2; ++i) {
#pragma unroll
    for (int j = 0; j < 2; ++j) {
#pragma unroll
      for (int r = 0; r < 16; ++r) {
        const int row = by * 128 + wm * 64 + i * 32 + ROW32(r, lane);  // token
        const int b = row >> 11, s = row & 2047;
        const int hcol = bx * 128 + wn * 64 + j * 32 + (lane & 31);    // 0..1023
        const float v = acc[i][j][r] + bias[2 * HDIM + hcol];
        vt[((size_t)b * HDIM + hcol) * S_LEN + s] = f2bf(v);
      }
    }
  }
}

// ---------- scores GEMM: sc = 32 * Q @ K^T + maskbias(key) ----------
__global__ __launch_bounds__(256, 2) void scores_kernel(
    const u16* __restrict__ qhi, const u16* __restrict__ qlo,
    const u16* __restrict__ khi, const u16* __restrict__ klo,
    const float* __restrict__ maskbias, float* __restrict__ scores)
{
  const int bx = blockIdx.x, by = blockIdx.y, b = blockIdx.z;
  f32x16 acc[2][2];
  const size_t qoff = ((size_t)b * S_LEN + by * 128) * HDIM;
  const size_t koff = ((size_t)b * S_LEN + bx * 128) * HDIM;
  gemm_core_split(qhi + qoff, qlo + qoff, khi + koff, klo + koff,
                  HDIM, HDIM, HDIM, acc);
  const int lane = threadIdx.x & 63, wave = threadIdx.x >> 6;
  const int wm = wave >> 1, wn = wave & 1;
#pragma unroll
  for (int i = 0; i < 2; ++i) {
#pragma unroll
    for (int j = 0; j < 2; ++j) {
#pragma unroll
      for (int r = 0; r < 16; ++r) {
        const int q   = by * 128 + wm * 64 + i * 32 + ROW32(r, lane);
        const int key = bx * 128 + wn * 64 + j * 32 + (lane & 31);
        scores[((size_t)b * S_LEN + q) * S_LEN + key] =
            32.0f * acc[i][j][r] + maskbias[b * S_LEN + key];
      }
    }
  }
}

// ---------- block reductions ----------
__device__ __forceinline__ float block_reduce_max(float v) {
#pragma unroll
  for (int o = 32; o > 0; o >>= 1) v = fmaxf(v, __shfl_down(v, o));
  __shared__ float tmp[4]; __shared__ float res;
  if ((threadIdx.x & 63) == 0) tmp[threadIdx.x >> 6] = v;
  __syncthreads();
  if (threadIdx.x == 0) res = fmaxf(fmaxf(tmp[0], tmp[1]), fmaxf(tmp[2], tmp[3]));
  __syncthreads();
  return res;
}
__device__ __forceinline__ float block_reduce_sum(float v) {
#pragma unroll
  for (int o = 32; o > 0; o >>= 1) v += __shfl_down(v, o);
  __shared__ float tmp[4]; __shared__ float res;
  if ((threadIdx.x & 63) == 0) tmp[threadIdx.x >> 6] = v;
  __syncthreads();
  if (threadIdx.x == 0) res = tmp[0] + tmp[1] + tmp[2] + tmp[3];
  __syncthreads();
  return res;
}

// ---------- softmax, in-place fp32 row -> bf16 P (row stride stays 8KB) ----------
__global__ __launch_bounds__(256) void softmax_kernel(float* __restrict__ scores) {
  const int row = blockIdx.x;              // 0..NTOK-1
  float* srow = scores + (size_t)row * S_LEN;
  const int t = threadIdx.x;
  const f32x4 v0 = ((const f32x4*)srow)[t];        // elems 4t..4t+3
  const f32x4 v1 = ((const f32x4*)srow)[256 + t];  // elems 1024+4t..

  float m = fmaxf(fmaxf(v0[0], v0[1]), fmaxf(v0[2], v0[3]));
  m = fmaxf(m, fmaxf(fmaxf(v1[0], v1[1]), fmaxf(v1[2], v1[3])));
  const float rowmax = block_reduce_max(m);

  float e[8];
#pragma unroll
  for (int c = 0; c < 4; ++c) e[c]     = expf(v0[c] - rowmax);
#pragma unroll
  for (int c = 0; c < 4; ++c) e[4 + c] = expf(v1[c] - rowmax);
  float s = 0.f;
#pragma unroll
  for (int c = 0; c < 8; ++c) s += e[c];
  const float inv = 1.0f / block_reduce_sum(s);

  u16* prow = (u16*)srow;   // bf16 row at same base; valid elems 0..2047, stride 4096
  u16x4 o0 = { f2bf(e[0] * inv), f2bf(e[1] * inv), f2bf(e[2] * inv), f2bf(e[3] * inv) };
  u16x4 o1 = { f2bf(e[4] * inv), f2bf(e[5] * inv), f2bf(e[6] * inv), f2bf(e[7] * inv) };
  ((u16x4*)prow)[t] = o0;
  ((u16x4*)prow)[256 + t] = o1;
}

// ---------- PV GEMM: out = P @ Vt^T ----------
__global__ __launch_bounds__(256, 2) void pv_kernel(
    const u16* __restrict__ P, const u16* __restrict__ vt, float* __restrict__ out)
{
  const int bx = blockIdx.x, by = blockIdx.y, b = blockIdx.z;
  f32x16 acc[2][2];
  gemm_core_plain(P + ((size_t)b * S_LEN + by * 128) * (2 * S_LEN),
                  vt + ((size_t)b * HDIM + bx * 128) * S_LEN,
                  2 * S_LEN, S_LEN, S_LEN, acc);
  const int lane = threadIdx.x & 63, wave = threadIdx.x >> 6;
  const int wm = wave >> 1, wn = wave & 1;
#pragma unroll
  for (int i = 0; i < 2; ++i) {
#pragma unroll
    for (int j = 0; j < 2; ++j) {
#pragma unroll
      for (int r = 0; r < 16; ++r) {
        const int q = by * 128 + wm * 64 + i * 32 + ROW32(r, lane);
        const int h = bx * 128 + wn * 64 + j * 32 + (lane & 31);
        out[((size_t)b * S_LEN + q) * HDIM + h] = acc[i][j][r];
      }
    }
  }
}

extern "C" void kernel_launch(void* const* d_in, const int* in_sizes, int n_in,
                              void* d_out, int out_size, void* d_ws, size_t ws_size,
                              hipStream_t stream)
{
  const float* qkv  = (const float*)d_in[0];
  const void*  mask = d_in[1];
  const float* W    = (const float*)d_in[2];
  const float* bias = (const float*)d_in[3];
  float* out = (float*)d_out;
  char* ws = (char*)d_ws;

  const size_t off_mask = 0;
  const size_t off_Whi  = 32768;
  const size_t off_Wlo  = off_Whi + (size_t)N3H * DIN * 2;
  const size_t off_Qhi  = off_Wlo + (size_t)N3H * DIN * 2;
  const size_t off_Qlo  = off_Qhi + (size_t)NTOK * HDIM * 2;
  const size_t off_Khi  = off_Qlo + (size_t)NTOK * HDIM * 2;
  const size_t off_Klo  = off_Khi + (size_t)NTOK * HDIM * 2;
  const size_t off_Vt   = off_Klo + (size_t)NTOK * HDIM * 2;
  const size_t off_A    = off_Vt + (size_t)NTOK * HDIM * 2;
  const size_t off_Alo  = off_A + (size_t)NTOK * DIN * 2;
  const size_t off_sc   = off_A;  // scores (67MB) overlay A-split (dead after proj)
  // total ws requirement: off_A + BATCH*S*S*4 = ~156 MiB

  float* maskbias = (float*)(ws + off_mask);
  u16* Whi = (u16*)(ws + off_Whi);  u16* Wlo = (u16*)(ws + off_Wlo);
  u16* Qhi = (u16*)(ws + off_Qhi);  u16* Qlo = (u16*)(ws + off_Qlo);
  u16* Khi = (u16*)(ws + off_Khi);  u16* Klo = (u16*)(ws + off_Klo);
  u16* Vt  = (u16*)(ws + off_Vt);
  u16* Ahi = (u16*)(ws + off_A);    u16* Alo = (u16*)(ws + off_Alo);
  float* scores = (float*)(ws + off_sc);

  prep_mask_kernel<<<1, 256, 0, stream>>>((const unsigned char*)mask, maskbias);
  split_f32_kernel<<<NTOK * DIN / 1024, 256, 0, stream>>>(qkv, Ahi, Alo);
  splitWT_kernel<<<N3H * DIN / 256, 256, 0, stream>>>(W, Whi, Wlo);
  proj_qk_kernel<<<dim3(2 * HDIM / 128, NTOK / 128, 1), 256, 0, stream>>>(
      Ahi, Alo, Whi, Wlo, bias, Qhi, Qlo, Khi, Klo);
  proj_v_kernel<<<dim3(HDIM / 128, NTOK / 128, 1), 256, 0, stream>>>(
      Ahi, Whi, bias, Vt);
  scores_kernel<<<dim3(S_LEN / 128, S_LEN / 128, BATCH), 256, 0, stream>>>(
      Qhi, Qlo, Khi, Klo, maskbias, scores);
  softmax_kernel<<<NTOK, 256, 0, stream>>>(scores);
  pv_kernel<<<dim3(HDIM / 128, S_LEN / 128, BATCH), 256, 0, stream>>>(
      (const u16*)scores, Vt, out);
}

// Round 6
// 457.187 us; speedup vs baseline: 1.0297x; 1.0297x over previous
//
#include <hip/hip_runtime.h>
#include <stdint.h>

// Problem: B=4, S=2048, D_IN=1024, H=1024; fp32 in/out.
// Pipeline: [prep_mask] [split qkv->bf16 hi/lo] [split+transpose W]
//           [proj_qk GEMM split-bf16 -> Qhi/Qlo/Khi/Klo]
//           [proj_v GEMM plain bf16 -> Vt]
//           [scores GEMM split-bf16 *32 + maskbias -> fp32 scores]
//           [softmax in-place -> bf16 P]   [PV GEMM bf16 -> out]
// NOTE (R3): GEMM __launch_bounds__ min-waves stays 2 — 4 blocks/CU blows the
// per-XCD L2 (FETCH 149->223MB, WRITE 99->421MB, MfmaUtil 35->23%).
// R5: 32x32x16 MFMA tripled LDS bank conflicts (lanes 0..31 share one k-block
// slot -> 16-way on 1/4 of banks). R6: XOR-swizzle the k-block slot by
// ((row>>1)&3) in both staging and frag reads -> uniform 8-way floor.

#define S_LEN 2048
#define BATCH 4
#define DIN   1024
#define HDIM  1024
#define N3H   3072
#define NTOK  8192   // BATCH*S_LEN

typedef unsigned short u16;
typedef __attribute__((ext_vector_type(8))) short bf16x8;
typedef __attribute__((ext_vector_type(4))) float f32x4;
typedef __attribute__((ext_vector_type(16))) float f32x16;
typedef __attribute__((ext_vector_type(4))) unsigned short u16x4;

// ---------- bf16 helpers (bit ops, RN) ----------
__device__ __forceinline__ u16 f2bf(float x) {
  union { float f; unsigned u; } c; c.f = x;
  unsigned r = c.u + 0x7fffu + ((c.u >> 16) & 1u);
  return (u16)(r >> 16);
}
__device__ __forceinline__ float bf2f(u16 h) {
  union { unsigned u; float f; } c; c.u = ((unsigned)h) << 16;
  return c.f;
}

// ---------- async global->LDS, width 16 ----------
__device__ __forceinline__ void gload16(const void* g, void* lds) {
  auto* gp = reinterpret_cast<const __attribute__((address_space(1))) void*>(
      reinterpret_cast<uintptr_t>(g));
  auto* lp = reinterpret_cast<__attribute__((address_space(3))) void*>(
      (unsigned)reinterpret_cast<uintptr_t>(lds));
  __builtin_amdgcn_global_load_lds(gp, lp, 16, 0, 0);
}

// Stage a 128x32 bf16 tile (row-major, row stride ld elems) into LDS.
// Swizzled layout: element (row, kb=k/8) lives at byte row*64 + ((kb ^ ((row>>1)&3))*16).
// LDS dest of instr i is the contiguous 1KB [i*1024, i*1024+1024) = rows i*16..i*16+15;
// lane l covers (row = i*16 + (l>>2), slot = l&3) -> logical kb = (l&3) ^ ((l>>3)&3)
// (since (row>>1)&3 = (l>>3)&3 for these rows). Same 64B global segments as
// unswizzled (lane order permuted within 4-lane groups) -> coalescing unchanged.
__device__ __forceinline__ void stage_tile(const u16* __restrict__ g, int ld,
                                           u16* lds, int wave, int lane) {
  const int rlane = lane >> 2;                            // 0..15
  const int kb    = (lane & 3) ^ ((lane >> 3) & 3);       // swizzled k-block
#pragma unroll
  for (int h = 0; h < 2; ++h) {
    const int instr = wave * 2 + h;  // 0..7
    const u16* gp = g + (size_t)(instr * 16 + rlane) * ld + kb * 8;
    gload16(gp, (char*)lds + instr * 1024);
  }
}

// 32x32x16 fragment fetch from the swizzled [128][32] LDS tile.
// A-operand layout: A[m=lane&31][k=(lane>>5)*8+j] (R5-verified, absmax passed).
// Wave tile 64x64 at (wm*64, wn*64); sub-tile i/j in {0,1}; k-half kh in {0,1}.
// Swizzle uses ((lane&31)>>1)&3 (tile-base rows are multiples of 32 -> no contribution).
__device__ __forceinline__ bf16x8 frag32(const u16* t, int wq, int sub, int kh,
                                         int lane) {
  const int r5   = lane & 31;
  const int row  = wq * 64 + sub * 32 + r5;
  const int slot = (kh * 2 + (lane >> 5)) ^ ((r5 >> 1) & 3);
  return *(const bf16x8*)(t + row * 32 + slot * 8);
}

// ---------- split-precision gemm_bt core: C(128x128) += (Ah+Al)*(Bh+Bl)^T ----------
// 3 MFMA products (hh, hl, lh); lo*lo dropped (2^-18 rel, negligible).
__device__ __forceinline__ void gemm_core_split(
    const u16* __restrict__ Ah, const u16* __restrict__ Al,
    const u16* __restrict__ Bh, const u16* __restrict__ Bl,
    int lda, int ldb, int K, f32x16 acc[2][2])
{
  __shared__ __align__(16) u16 lds[4 * 4096];  // aH | aL | bH | bL, 8KB each
  u16* aH = lds;          u16* aL = lds + 4096;
  u16* bH = lds + 8192;   u16* bL = lds + 12288;
  const int tid  = threadIdx.x;
  const int wave = tid >> 6, lane = tid & 63;
  const int wm = wave >> 1, wn = wave & 1;

#pragma unroll
  for (int i = 0; i < 2; ++i)
#pragma unroll
    for (int j = 0; j < 2; ++j)
#pragma unroll
      for (int r = 0; r < 16; ++r) acc[i][j][r] = 0.f;

  for (int k0 = 0; k0 < K; k0 += 32) {
    stage_tile(Ah + k0, lda, aH, wave, lane);
    stage_tile(Al + k0, lda, aL, wave, lane);
    stage_tile(Bh + k0, ldb, bH, wave, lane);
    stage_tile(Bl + k0, ldb, bL, wave, lane);
    __syncthreads();   // drains vmcnt (global_load_lds) before LDS reads

#pragma unroll
    for (int kh = 0; kh < 2; ++kh) {
      bf16x8 fah[2], fal[2];
#pragma unroll
      for (int i = 0; i < 2; ++i) {
        fah[i] = frag32(aH, wm, i, kh, lane);
        fal[i] = frag32(aL, wm, i, kh, lane);
      }
#pragma unroll
      for (int j = 0; j < 2; ++j) {
        const bf16x8 fbh = frag32(bH, wn, j, kh, lane);
        const bf16x8 fbl = frag32(bL, wn, j, kh, lane);
#pragma unroll
        for (int i = 0; i < 2; ++i) {
          acc[i][j] = __builtin_amdgcn_mfma_f32_32x32x16_bf16(fah[i], fbh, acc[i][j], 0, 0, 0);
          acc[i][j] = __builtin_amdgcn_mfma_f32_32x32x16_bf16(fah[i], fbl, acc[i][j], 0, 0, 0);
          acc[i][j] = __builtin_amdgcn_mfma_f32_32x32x16_bf16(fal[i], fbh, acc[i][j], 0, 0, 0);
        }
      }
    }
    __syncthreads();   // protect LDS before next stage
  }
}

// ---------- plain bf16 gemm_bt core ----------
__device__ __forceinline__ void gemm_core_plain(
    const u16* __restrict__ A, const u16* __restrict__ B,
    int lda, int ldb, int K, f32x16 acc[2][2])
{
  __shared__ __align__(16) u16 lds[2 * 4096];
  u16* aT = lds; u16* bT = lds + 4096;
  const int tid  = threadIdx.x;
  const int wave = tid >> 6, lane = tid & 63;
  const int wm = wave >> 1, wn = wave & 1;

#pragma unroll
  for (int i = 0; i < 2; ++i)
#pragma unroll
    for (int j = 0; j < 2; ++j)
#pragma unroll
      for (int r = 0; r < 16; ++r) acc[i][j][r] = 0.f;

  for (int k0 = 0; k0 < K; k0 += 32) {
    stage_tile(A + k0, lda, aT, wave, lane);
    stage_tile(B + k0, ldb, bT, wave, lane);
    __syncthreads();
#pragma unroll
    for (int kh = 0; kh < 2; ++kh) {
      bf16x8 fa[2];
#pragma unroll
      for (int i = 0; i < 2; ++i) fa[i] = frag32(aT, wm, i, kh, lane);
#pragma unroll
      for (int j = 0; j < 2; ++j) {
        const bf16x8 fb = frag32(bT, wn, j, kh, lane);
#pragma unroll
        for (int i = 0; i < 2; ++i)
          acc[i][j] = __builtin_amdgcn_mfma_f32_32x32x16_bf16(fa[i], fb, acc[i][j], 0, 0, 0);
      }
    }
    __syncthreads();
  }
}

// C/D layout for 32x32 (HW-verified m74/m101):
//   col = lane&31, row = (reg&3) + 8*(reg>>2) + 4*(lane>>5)
#define ROW32(r, lane) (((r) & 3) + 8 * ((r) >> 2) + 4 * ((lane) >> 5))

// ---------- mask prep: detect bool(1B) vs int32(4B) repr, write additive bias ----------
__global__ void prep_mask_kernel(const unsigned char* __restrict__ m,
                                 float* __restrict__ bias) {
  __shared__ int isBool;
  if (threadIdx.x == 0) isBool = 0;
  __syncthreads();
  for (int i = threadIdx.x; i < NTOK; i += 256)
    if ((i & 3) && m[i]) isBool = 1;   // int32 repr of 0/1 has zero bytes at %4!=0
  __syncthreads();
  const int stride = isBool ? 1 : 4;
  const float ninf = -__builtin_inff();
  for (int i = threadIdx.x; i < NTOK; i += 256)
    bias[i] = m[(size_t)i * stride] ? ninf : 0.f;
}

// ---------- split fp32 -> bf16 hi/lo ----------
__global__ __launch_bounds__(256) void split_f32_kernel(
    const float* __restrict__ x, u16* __restrict__ hi, u16* __restrict__ lo) {
  const int i = (blockIdx.x * 256 + threadIdx.x) * 4;
  const f32x4 v = *(const f32x4*)(x + i);
  u16x4 h, l;
#pragma unroll
  for (int c = 0; c < 4; ++c) {
    h[c] = f2bf(v[c]);
    l[c] = f2bf(v[c] - bf2f(h[c]));
  }
  *(u16x4*)(hi + i) = h;
  *(u16x4*)(lo + i) = l;
}

// ---------- transpose + split W (DINxN3H -> N3HxDIN) ----------
__global__ __launch_bounds__(256) void splitWT_kernel(
    const float* __restrict__ W, u16* __restrict__ whi, u16* __restrict__ wlo) {
  const int o = blockIdx.x * 256 + threadIdx.x;  // o = n*DIN + d
  const int n = o >> 10, d = o & 1023;
  const float v = W[(size_t)d * N3H + n];
  const u16 h = f2bf(v);
  whi[o] = h;
  wlo[o] = f2bf(v - bf2f(h));
}

// ---------- projection GEMM (Q,K thirds): split precision ----------
__global__ __launch_bounds__(256, 2) void proj_qk_kernel(
    const u16* __restrict__ Ahi, const u16* __restrict__ Alo,
    const u16* __restrict__ Whi, const u16* __restrict__ Wlo,
    const float* __restrict__ bias,
    u16* __restrict__ qhi, u16* __restrict__ qlo,
    u16* __restrict__ khi, u16* __restrict__ klo)
{
  const int bx = blockIdx.x, by = blockIdx.y;  // bx over 16 tiles (cols 0..2047)
  f32x16 acc[2][2];
  gemm_core_split(Ahi + (size_t)by * 128 * DIN, Alo + (size_t)by * 128 * DIN,
                  Whi + (size_t)bx * 128 * DIN, Wlo + (size_t)bx * 128 * DIN,
                  DIN, DIN, DIN, acc);
  const int lane = threadIdx.x & 63, wave = threadIdx.x >> 6;
  const int wm = wave >> 1, wn = wave & 1;
#pragma unroll
  for (int i = 0; i < 2; ++i) {
#pragma unroll
    for (int j = 0; j < 2; ++j) {
#pragma unroll
      for (int r = 0; r < 16; ++r) {
        const int row = by * 128 + wm * 64 + i * 32 + ROW32(r, lane);  // token
        const int col = bx * 128 + wn * 64 + j * 32 + (lane & 31);     // 0..2047
        const float v = acc[i][j][r] + bias[col];
        const u16 h = f2bf(v);
        const u16 l = f2bf(v - bf2f(h));
        if (col < HDIM) {                       // Q (block-uniform branch)
          const size_t idx = (size_t)row * HDIM + col;
          qhi[idx] = h; qlo[idx] = l;
        } else {                                // K
          const size_t idx = (size_t)row * HDIM + (col - HDIM);
          khi[idx] = h; klo[idx] = l;
        }
      }
    }
  }
}

// ---------- projection GEMM (V third): plain bf16, writes V transposed ----------
__global__ __launch_bounds__(256, 2) void proj_v_kernel(
    const u16* __restrict__ Ahi, const u16* __restrict__ Whi,
    const float* __restrict__ bias, u16* __restrict__ vt)
{
  const int bx = blockIdx.x, by = blockIdx.y;  // bx over 8 tiles (cols 2048..3071)
  f32x16 acc[2][2];
  gemm_core_plain(Ahi + (size_t)by * 128 * DIN,
                  Whi + (size_t)(2048 + bx * 128) * DIN,
                  DIN, DIN, DIN, acc);
  const int lane = threadIdx.x & 63, wave = threadIdx.x >> 6;
  const int wm = wave >> 1, wn = wave & 1;
#pragma unroll
  for (int i = 0; i < 2; ++i) {
#pragma unroll
    for (int j = 0; j < 2; ++j) {
#pragma unroll
      for (int r = 0; r < 16; ++r) {
        const int row = by * 128 + wm * 64 + i * 32 + ROW32(r, lane);  // token
        const int b = row >> 11, s = row & 2047;
        const int hcol = bx * 128 + wn * 64 + j * 32 + (lane & 31);    // 0..1023
        const float v = acc[i][j][r] + bias[2 * HDIM + hcol];
        vt[((size_t)b * HDIM + hcol) * S_LEN + s] = f2bf(v);
      }
    }
  }
}

// ---------- scores GEMM: sc = 32 * Q @ K^T + maskbias(key) ----------
__global__ __launch_bounds__(256, 2) void scores_kernel(
    const u16* __restrict__ qhi, const u16* __restrict__ qlo,
    const u16* __restrict__ khi, const u16* __restrict__ klo,
    const float* __restrict__ maskbias, float* __restrict__ scores)
{
  const int bx = blockIdx.x, by = blockIdx.y, b = blockIdx.z;
  f32x16 acc[2][2];
  const size_t qoff = ((size_t)b * S_LEN + by * 128) * HDIM;
  const size_t koff = ((size_t)b * S_LEN + bx * 128) * HDIM;
  gemm_core_split(qhi + qoff, qlo + qoff, khi + koff, klo + koff,
                  HDIM, HDIM, HDIM, acc);
  const int lane = threadIdx.x & 63, wave = threadIdx.x >> 6;
  const int wm = wave >> 1, wn = wave & 1;
#pragma unroll
  for (int i = 0; i < 2; ++i) {
#pragma unroll
    for (int j = 0; j < 2; ++j) {
#pragma unroll
      for (int r = 0; r < 16; ++r) {
        const int q   = by * 128 + wm * 64 + i * 32 + ROW32(r, lane);
        const int key = bx * 128 + wn * 64 + j * 32 + (lane & 31);
        scores[((size_t)b * S_LEN + q) * S_LEN + key] =
            32.0f * acc[i][j][r] + maskbias[b * S_LEN + key];
      }
    }
  }
}

// ---------- block reductions ----------
__device__ __forceinline__ float block_reduce_max(float v) {
#pragma unroll
  for (int o = 32; o > 0; o >>= 1) v = fmaxf(v, __shfl_down(v, o));
  __shared__ float tmp[4]; __shared__ float res;
  if ((threadIdx.x & 63) == 0) tmp[threadIdx.x >> 6] = v;
  __syncthreads();
  if (threadIdx.x == 0) res = fmaxf(fmaxf(tmp[0], tmp[1]), fmaxf(tmp[2], tmp[3]));
  __syncthreads();
  return res;
}
__device__ __forceinline__ float block_reduce_sum(float v) {
#pragma unroll
  for (int o = 32; o > 0; o >>= 1) v += __shfl_down(v, o);
  __shared__ float tmp[4]; __shared__ float res;
  if ((threadIdx.x & 63) == 0) tmp[threadIdx.x >> 6] = v;
  __syncthreads();
  if (threadIdx.x == 0) res = tmp[0] + tmp[1] + tmp[2] + tmp[3];
  __syncthreads();
  return res;
}

// ---------- softmax, in-place fp32 row -> bf16 P (row stride stays 8KB) ----------
__global__ __launch_bounds__(256) void softmax_kernel(float* __restrict__ scores) {
  const int row = blockIdx.x;              // 0..NTOK-1
  float* srow = scores + (size_t)row * S_LEN;
  const int t = threadIdx.x;
  const f32x4 v0 = ((const f32x4*)srow)[t];        // elems 4t..4t+3
  const f32x4 v1 = ((const f32x4*)srow)[256 + t];  // elems 1024+4t..

  float m = fmaxf(fmaxf(v0[0], v0[1]), fmaxf(v0[2], v0[3]));
  m = fmaxf(m, fmaxf(fmaxf(v1[0], v1[1]), fmaxf(v1[2], v1[3])));
  const float rowmax = block_reduce_max(m);

  float e[8];
#pragma unroll
  for (int c = 0; c < 4; ++c) e[c]     = expf(v0[c] - rowmax);
#pragma unroll
  for (int c = 0; c < 4; ++c) e[4 + c] = expf(v1[c] - rowmax);
  float s = 0.f;
#pragma unroll
  for (int c = 0; c < 8; ++c) s += e[c];
  const float inv = 1.0f / block_reduce_sum(s);

  u16* prow = (u16*)srow;   // bf16 row at same base; valid elems 0..2047, stride 4096
  u16x4 o0 = { f2bf(e[0] * inv), f2bf(e[1] * inv), f2bf(e[2] * inv), f2bf(e[3] * inv) };
  u16x4 o1 = { f2bf(e[4] * inv), f2bf(e[5] * inv), f2bf(e[6] * inv), f2bf(e[7] * inv) };
  ((u16x4*)prow)[t] = o0;
  ((u16x4*)prow)[256 + t] = o1;
}

// ---------- PV GEMM: out = P @ Vt^T ----------
__global__ __launch_bounds__(256, 2) void pv_kernel(
    const u16* __restrict__ P, const u16* __restrict__ vt, float* __restrict__ out)
{
  const int bx = blockIdx.x, by = blockIdx.y, b = blockIdx.z;
  f32x16 acc[2][2];
  gemm_core_plain(P + ((size_t)b * S_LEN + by * 128) * (2 * S_LEN),
                  vt + ((size_t)b * HDIM + bx * 128) * S_LEN,
                  2 * S_LEN, S_LEN, S_LEN, acc);
  const int lane = threadIdx.x & 63, wave = threadIdx.x >> 6;
  const int wm = wave >> 1, wn = wave & 1;
#pragma unroll
  for (int i = 0; i < 2; ++i) {
#pragma unroll
    for (int j = 0; j < 2; ++j) {
#pragma unroll
      for (int r = 0; r < 16; ++r) {
        const int q = by * 128 + wm * 64 + i * 32 + ROW32(r, lane);
        const int h = bx * 128 + wn * 64 + j * 32 + (lane & 31);
        out[((size_t)b * S_LEN + q) * HDIM + h] = acc[i][j][r];
      }
    }
  }
}

extern "C" void kernel_launch(void* const* d_in, const int* in_sizes, int n_in,
                              void* d_out, int out_size, void* d_ws, size_t ws_size,
                              hipStream_t stream)
{
  const float* qkv  = (const float*)d_in[0];
  const void*  mask = d_in[1];
  const float* W    = (const float*)d_in[2];
  const float* bias = (const float*)d_in[3];
  float* out = (float*)d_out;
  char* ws = (char*)d_ws;

  const size_t off_mask = 0;
  const size_t off_Whi  = 32768;
  const size_t off_Wlo  = off_Whi + (size_t)N3H * DIN * 2;
  const size_t off_Qhi  = off_Wlo + (size_t)N3H * DIN * 2;
  const size_t off_Qlo  = off_Qhi + (size_t)NTOK * HDIM * 2;
  const size_t off_Khi  = off_Qlo + (size_t)NTOK * HDIM * 2;
  const size_t off_Klo  = off_Khi + (size_t)NTOK * HDIM * 2;
  const size_t off_Vt   = off_Klo + (size_t)NTOK * HDIM * 2;
  const size_t off_A    = off_Vt + (size_t)NTOK * HDIM * 2;
  const size_t off_Alo  = off_A + (size_t)NTOK * DIN * 2;
  const size_t off_sc   = off_A;  // scores (67MB) overlay A-split (dead after proj)
  // total ws requirement: off_A + BATCH*S*S*4 = ~156 MiB

  float* maskbias = (float*)(ws + off_mask);
  u16* Whi = (u16*)(ws + off_Whi);  u16* Wlo = (u16*)(ws + off_Wlo);
  u16* Qhi = (u16*)(ws + off_Qhi);  u16* Qlo = (u16*)(ws + off_Qlo);
  u16* Khi = (u16*)(ws + off_Khi);  u16* Klo = (u16*)(ws + off_Klo);
  u16* Vt  = (u16*)(ws + off_Vt);
  u16* Ahi = (u16*)(ws + off_A);    u16* Alo = (u16*)(ws + off_Alo);
  float* scores = (float*)(ws + off_sc);

  prep_mask_kernel<<<1, 256, 0, stream>>>((const unsigned char*)mask, maskbias);
  split_f32_kernel<<<NTOK * DIN / 1024, 256, 0, stream>>>(qkv, Ahi, Alo);
  splitWT_kernel<<<N3H * DIN / 256, 256, 0, stream>>>(W, Whi, Wlo);
  proj_qk_kernel<<<dim3(2 * HDIM / 128, NTOK / 128, 1), 256, 0, stream>>>(
      Ahi, Alo, Whi, Wlo, bias, Qhi, Qlo, Khi, Klo);
  proj_v_kernel<<<dim3(HDIM / 128, NTOK / 128, 1), 256, 0, stream>>>(
      Ahi, Whi, bias, Vt);
  scores_kernel<<<dim3(S_LEN / 128, S_LEN / 128, BATCH), 256, 0, stream>>>(
      Qhi, Qlo, Khi, Klo, maskbias, scores);
  softmax_kernel<<<NTOK, 256, 0, stream>>>(scores);
  pv_kernel<<<dim3(HDIM / 128, S_LEN / 128, BATCH), 256, 0, stream>>>(
      (const u16*)scores, Vt, out);
}

// Round 7
// 444.564 us; speedup vs baseline: 1.0589x; 1.0284x over previous
//
#include <hip/hip_runtime.h>
#include <stdint.h>

// Problem: B=4, S=2048, D_IN=1024, H=1024; fp32 in/out.
// Pipeline: [prep_mask] [split qkv->bf16 hi/lo] [split+transpose W]
//           [proj_qk GEMM split-bf16 -> Qhi/Qlo/Khi/Klo]
//           [proj_v GEMM plain bf16 -> Vt]
//           [scores GEMM split-bf16 *32 + maskbias -> fp32 scores]
//           [softmax in-place -> bf16 P]   [PV GEMM bf16 -> out]
// R3: GEMM __launch_bounds__ stays (256,2) — 4 blocks/CU blows per-XCD L2.
// R6: 32x32x16 MFMA + XOR swizzle -> conflicts at the uniform floor (8.4M).
// R7: BK 32->64 — halves the per-iter barrier/vmcnt-drain count (the measured
//     bottleneck: MFMA floor 41us, LDS 27us, but kernel 123us). LDS 64KB/block,
//     2 blocks/CU = 128KB <= 160KB.

#define S_LEN 2048
#define BATCH 4
#define DIN   1024
#define HDIM  1024
#define N3H   3072
#define NTOK  8192   // BATCH*S_LEN

typedef unsigned short u16;
typedef __attribute__((ext_vector_type(8))) short bf16x8;
typedef __attribute__((ext_vector_type(4))) float f32x4;
typedef __attribute__((ext_vector_type(16))) float f32x16;
typedef __attribute__((ext_vector_type(4))) unsigned short u16x4;

// ---------- bf16 helpers (bit ops, RN) ----------
__device__ __forceinline__ u16 f2bf(float x) {
  union { float f; unsigned u; } c; c.f = x;
  unsigned r = c.u + 0x7fffu + ((c.u >> 16) & 1u);
  return (u16)(r >> 16);
}
__device__ __forceinline__ float bf2f(u16 h) {
  union { unsigned u; float f; } c; c.u = ((unsigned)h) << 16;
  return c.f;
}

// ---------- async global->LDS, width 16 ----------
__device__ __forceinline__ void gload16(const void* g, void* lds) {
  auto* gp = reinterpret_cast<const __attribute__((address_space(1))) void*>(
      reinterpret_cast<uintptr_t>(g));
  auto* lp = reinterpret_cast<__attribute__((address_space(3))) void*>(
      (unsigned)reinterpret_cast<uintptr_t>(lds));
  __builtin_amdgcn_global_load_lds(gp, lp, 16, 0, 0);
}

// Stage a 128x64 bf16 tile (row-major, row stride ld elems) into swizzled LDS.
// Layout: element (row, kb=k/8) at byte row*128 + ((kb ^ (row&7))*16).
// 16 instrs of 1KB (4 waves x 4); instr i = rows i*8..i*8+7. Lane l covers
// (row=i*8+(l>>3), slot=l&7) -> logical kb = (l&7)^((l>>3)&7). Each 8-lane
// group reads one full 128B row (permuted within it) -> coalescing unchanged.
__device__ __forceinline__ void stage_tile(const u16* __restrict__ g, int ld,
                                           u16* lds, int wave, int lane) {
  const int rlane = lane >> 3;                       // 0..7: row within instr
  const int kb    = (lane & 7) ^ (rlane & 7);        // swizzled k-block
#pragma unroll
  for (int h = 0; h < 4; ++h) {
    const int instr = wave * 4 + h;                  // 0..15
    const u16* gp = g + (size_t)(instr * 8 + rlane) * ld + kb * 8;
    gload16(gp, (char*)lds + instr * 1024);
  }
}

// 32x32x16 fragment fetch from swizzled [128][64] LDS tile.
// A-operand layout: A[m=lane&31][k=(lane>>5)*8+j] (R5/R6-verified).
// kh in 0..3 selects the 16-wide k-slice; kb = kh*2 + (lane>>5).
// Bank check: slot = kb ^ (r5&7) -> 8 slots x 4 lanes x (16B=4 banks)
// = 256 bank-accesses uniform over 32 banks (the wave64-b128 floor).
__device__ __forceinline__ bf16x8 frag32(const u16* t, int wq, int sub, int kh,
                                         int lane) {
  const int r5   = lane & 31;
  const int row  = wq * 64 + sub * 32 + r5;
  const int slot = (kh * 2 + (lane >> 5)) ^ (r5 & 7);
  return *(const bf16x8*)(t + row * 64 + slot * 8);
}

// ---------- split-precision gemm_bt core: C(128x128) += (Ah+Al)*(Bh+Bl)^T ----------
// 3 MFMA products (hh, hl, lh); lo*lo dropped (2^-18 rel, negligible).
__device__ __forceinline__ void gemm_core_split(
    const u16* __restrict__ Ah, const u16* __restrict__ Al,
    const u16* __restrict__ Bh, const u16* __restrict__ Bl,
    int lda, int ldb, int K, f32x16 acc[2][2])
{
  __shared__ __align__(16) u16 lds[4 * 8192];  // aH | aL | bH | bL, 16KB each
  u16* aH = lds;           u16* aL = lds + 8192;
  u16* bH = lds + 16384;   u16* bL = lds + 24576;
  const int tid  = threadIdx.x;
  const int wave = tid >> 6, lane = tid & 63;
  const int wm = wave >> 1, wn = wave & 1;

#pragma unroll
  for (int i = 0; i < 2; ++i)
#pragma unroll
    for (int j = 0; j < 2; ++j)
#pragma unroll
      for (int r = 0; r < 16; ++r) acc[i][j][r] = 0.f;

  for (int k0 = 0; k0 < K; k0 += 64) {
    stage_tile(Ah + k0, lda, aH, wave, lane);
    stage_tile(Al + k0, lda, aL, wave, lane);
    stage_tile(Bh + k0, ldb, bH, wave, lane);
    stage_tile(Bl + k0, ldb, bL, wave, lane);
    __syncthreads();   // drains vmcnt (global_load_lds) before LDS reads

#pragma unroll
    for (int kh = 0; kh < 4; ++kh) {
      bf16x8 fah[2], fal[2];
#pragma unroll
      for (int i = 0; i < 2; ++i) {
        fah[i] = frag32(aH, wm, i, kh, lane);
        fal[i] = frag32(aL, wm, i, kh, lane);
      }
#pragma unroll
      for (int j = 0; j < 2; ++j) {
        const bf16x8 fbh = frag32(bH, wn, j, kh, lane);
        const bf16x8 fbl = frag32(bL, wn, j, kh, lane);
#pragma unroll
        for (int i = 0; i < 2; ++i) {
          acc[i][j] = __builtin_amdgcn_mfma_f32_32x32x16_bf16(fah[i], fbh, acc[i][j], 0, 0, 0);
          acc[i][j] = __builtin_amdgcn_mfma_f32_32x32x16_bf16(fah[i], fbl, acc[i][j], 0, 0, 0);
          acc[i][j] = __builtin_amdgcn_mfma_f32_32x32x16_bf16(fal[i], fbh, acc[i][j], 0, 0, 0);
        }
      }
    }
    __syncthreads();   // protect LDS before next stage
  }
}

// ---------- plain bf16 gemm_bt core ----------
__device__ __forceinline__ void gemm_core_plain(
    const u16* __restrict__ A, const u16* __restrict__ B,
    int lda, int ldb, int K, f32x16 acc[2][2])
{
  __shared__ __align__(16) u16 lds[2 * 8192];
  u16* aT = lds; u16* bT = lds + 8192;
  const int tid  = threadIdx.x;
  const int wave = tid >> 6, lane = tid & 63;
  const int wm = wave >> 1, wn = wave & 1;

#pragma unroll
  for (int i = 0; i < 2; ++i)
#pragma unroll
    for (int j = 0; j < 2; ++j)
#pragma unroll
      for (int r = 0; r < 16; ++r) acc[i][j][r] = 0.f;

  for (int k0 = 0; k0 < K; k0 += 64) {
    stage_tile(A + k0, lda, aT, wave, lane);
    stage_tile(B + k0, ldb, bT, wave, lane);
    __syncthreads();
#pragma unroll
    for (int kh = 0; kh < 4; ++kh) {
      bf16x8 fa[2];
#pragma unroll
      for (int i = 0; i < 2; ++i) fa[i] = frag32(aT, wm, i, kh, lane);
#pragma unroll
      for (int j = 0; j < 2; ++j) {
        const bf16x8 fb = frag32(bT, wn, j, kh, lane);
#pragma unroll
        for (int i = 0; i < 2; ++i)
          acc[i][j] = __builtin_amdgcn_mfma_f32_32x32x16_bf16(fa[i], fb, acc[i][j], 0, 0, 0);
      }
    }
    __syncthreads();
  }
}

// C/D layout for 32x32 (HW-verified m74/m101):
//   col = lane&31, row = (reg&3) + 8*(reg>>2) + 4*(lane>>5)
#define ROW32(r, lane) (((r) & 3) + 8 * ((r) >> 2) + 4 * ((lane) >> 5))

// ---------- mask prep: detect bool(1B) vs int32(4B) repr, write additive bias ----------
__global__ void prep_mask_kernel(const unsigned char* __restrict__ m,
                                 float* __restrict__ bias) {
  __shared__ int isBool;
  if (threadIdx.x == 0) isBool = 0;
  __syncthreads();
  for (int i = threadIdx.x; i < NTOK; i += 256)
    if ((i & 3) && m[i]) isBool = 1;   // int32 repr of 0/1 has zero bytes at %4!=0
  __syncthreads();
  const int stride = isBool ? 1 : 4;
  const float ninf = -__builtin_inff();
  for (int i = threadIdx.x; i < NTOK; i += 256)
    bias[i] = m[(size_t)i * stride] ? ninf : 0.f;
}

// ---------- split fp32 -> bf16 hi/lo ----------
__global__ __launch_bounds__(256) void split_f32_kernel(
    const float* __restrict__ x, u16* __restrict__ hi, u16* __restrict__ lo) {
  const int i = (blockIdx.x * 256 + threadIdx.x) * 4;
  const f32x4 v = *(const f32x4*)(x + i);
  u16x4 h, l;
#pragma unroll
  for (int c = 0; c < 4; ++c) {
    h[c] = f2bf(v[c]);
    l[c] = f2bf(v[c] - bf2f(h[c]));
  }
  *(u16x4*)(hi + i) = h;
  *(u16x4*)(lo + i) = l;
}

// ---------- transpose + split W (DINxN3H -> N3HxDIN) ----------
__global__ __launch_bounds__(256) void splitWT_kernel(
    const float* __restrict__ W, u16* __restrict__ whi, u16* __restrict__ wlo) {
  const int o = blockIdx.x * 256 + threadIdx.x;  // o = n*DIN + d
  const int n = o >> 10, d = o & 1023;
  const float v = W[(size_t)d * N3H + n];
  const u16 h = f2bf(v);
  whi[o] = h;
  wlo[o] = f2bf(v - bf2f(h));
}

// ---------- projection GEMM (Q,K thirds): split precision ----------
__global__ __launch_bounds__(256, 2) void proj_qk_kernel(
    const u16* __restrict__ Ahi, const u16* __restrict__ Alo,
    const u16* __restrict__ Whi, const u16* __restrict__ Wlo,
    const float* __restrict__ bias,
    u16* __restrict__ qhi, u16* __restrict__ qlo,
    u16* __restrict__ khi, u16* __restrict__ klo)
{
  const int bx = blockIdx.x, by = blockIdx.y;  // bx over 16 tiles (cols 0..2047)
  f32x16 acc[2][2];
  gemm_core_split(Ahi + (size_t)by * 128 * DIN, Alo + (size_t)by * 128 * DIN,
                  Whi + (size_t)bx * 128 * DIN, Wlo + (size_t)bx * 128 * DIN,
                  DIN, DIN, DIN, acc);
  const int lane = threadIdx.x & 63, wave = threadIdx.x >> 6;
  const int wm = wave >> 1, wn = wave & 1;
#pragma unroll
  for (int i = 0; i < 2; ++i) {
#pragma unroll
    for (int j = 0; j < 2; ++j) {
#pragma unroll
      for (int r = 0; r < 16; ++r) {
        const int row = by * 128 + wm * 64 + i * 32 + ROW32(r, lane);  // token
        const int col = bx * 128 + wn * 64 + j * 32 + (lane & 31);     // 0..2047
        const float v = acc[i][j][r] + bias[col];
        const u16 h = f2bf(v);
        const u16 l = f2bf(v - bf2f(h));
        if (col < HDIM) {                       // Q (block-uniform branch)
          const size_t idx = (size_t)row * HDIM + col;
          qhi[idx] = h; qlo[idx] = l;
        } else {                                // K
          const size_t idx = (size_t)row * HDIM + (col - HDIM);
          khi[idx] = h; klo[idx] = l;
        }
      }
    }
  }
}

// ---------- projection GEMM (V third): plain bf16, writes V transposed ----------
__global__ __launch_bounds__(256, 2) void proj_v_kernel(
    const u16* __restrict__ Ahi, const u16* __restrict__ Whi,
    const float* __restrict__ bias, u16* __restrict__ vt)
{
  const int bx = blockIdx.x, by = blockIdx.y;  // bx over 8 tiles (cols 2048..3071)
  f32x16 acc[2][2];
  gemm_core_plain(Ahi + (size_t)by * 128 * DIN,
                  Whi + (size_t)(2048 + bx * 128) * DIN,
                  DIN, DIN, DIN, acc);
  const int lane = threadIdx.x & 63, wave = threadIdx.x >> 6;
  const int wm = wave >> 1, wn = wave & 1;
#pragma unroll
  for (int i = 0; i < 2; ++i) {
#pragma unroll
    for (int j = 0; j < 2; ++j) {
#pragma unroll
      for (int r = 0; r < 16; ++r) {
        const int row = by * 128 + wm * 64 + i * 32 + ROW32(r, lane);  // token
        const int b = row >> 11, s = row & 2047;
        const int hcol = bx * 128 + wn * 64 + j * 32 + (lane & 31);    // 0..1023
        const float v = acc[i][j][r] + bias[2 * HDIM + hcol];
        vt[((size_t)b * HDIM + hcol) * S_LEN + s] = f2bf(v);
      }
    }
  }
}

// ---------- scores GEMM: sc = 32 * Q @ K^T + maskbias(key) ----------
__global__ __launch_bounds__(256, 2) void scores_kernel(
    const u16* __restrict__ qhi, const u16* __restrict__ qlo,
    const u16* __restrict__ khi, const u16* __restrict__ klo,
    const float* __restrict__ maskbias, float* __restrict__ scores)
{
  const int bx = blockIdx.x, by = blockIdx.y, b = blockIdx.z;
  f32x16 acc[2][2];
  const size_t qoff = ((size_t)b * S_LEN + by * 128) * HDIM;
  const size_t koff = ((size_t)b * S_LEN + bx * 128) * HDIM;
  gemm_core_split(qhi + qoff, qlo + qoff, khi + koff, klo + koff,
                  HDIM, HDIM, HDIM, acc);
  const int lane = threadIdx.x & 63, wave = threadIdx.x >> 6;
  const int wm = wave >> 1, wn = wave & 1;
#pragma unroll
  for (int i = 0; i < 2; ++i) {
#pragma unroll
    for (int j = 0; j < 2; ++j) {
#pragma unroll
      for (int r = 0; r < 16; ++r) {
        const int q   = by * 128 + wm * 64 + i * 32 + ROW32(r, lane);
        const int key = bx * 128 + wn * 64 + j * 32 + (lane & 31);
        scores[((size_t)b * S_LEN + q) * S_LEN + key] =
            32.0f * acc[i][j][r] + maskbias[b * S_LEN + key];
      }
    }
  }
}

// ---------- block reductions ----------
__device__ __forceinline__ float block_reduce_max(float v) {
#pragma unroll
  for (int o = 32; o > 0; o >>= 1) v = fmaxf(v, __shfl_down(v, o));
  __shared__ float tmp[4]; __shared__ float res;
  if ((threadIdx.x & 63) == 0) tmp[threadIdx.x >> 6] = v;
  __syncthreads();
  if (threadIdx.x == 0) res = fmaxf(fmaxf(tmp[0], tmp[1]), fmaxf(tmp[2], tmp[3]));
  __syncthreads();
  return res;
}
__device__ __forceinline__ float block_reduce_sum(float v) {
#pragma unroll
  for (int o = 32; o > 0; o >>= 1) v += __shfl_down(v, o);
  __shared__ float tmp[4]; __shared__ float res;
  if ((threadIdx.x & 63) == 0) tmp[threadIdx.x >> 6] = v;
  __syncthreads();
  if (threadIdx.x == 0) res = tmp[0] + tmp[1] + tmp[2] + tmp[3];
  __syncthreads();
  return res;
}

// ---------- softmax, in-place fp32 row -> bf16 P (row stride stays 8KB) ----------
__global__ __launch_bounds__(256) void softmax_kernel(float* __restrict__ scores) {
  const int row = blockIdx.x;              // 0..NTOK-1
  float* srow = scores + (size_t)row * S_LEN;
  const int t = threadIdx.x;
  const f32x4 v0 = ((const f32x4*)srow)[t];        // elems 4t..4t+3
  const f32x4 v1 = ((const f32x4*)srow)[256 + t];  // elems 1024+4t..

  float m = fmaxf(fmaxf(v0[0], v0[1]), fmaxf(v0[2], v0[3]));
  m = fmaxf(m, fmaxf(fmaxf(v1[0], v1[1]), fmaxf(v1[2], v1[3])));
  const float rowmax = block_reduce_max(m);

  float e[8];
#pragma unroll
  for (int c = 0; c < 4; ++c) e[c]     = expf(v0[c] - rowmax);
#pragma unroll
  for (int c = 0; c < 4; ++c) e[4 + c] = expf(v1[c] - rowmax);
  float s = 0.f;
#pragma unroll
  for (int c = 0; c < 8; ++c) s += e[c];
  const float inv = 1.0f / block_reduce_sum(s);

  u16* prow = (u16*)srow;   // bf16 row at same base; valid elems 0..2047, stride 4096
  u16x4 o0 = { f2bf(e[0] * inv), f2bf(e[1] * inv), f2bf(e[2] * inv), f2bf(e[3] * inv) };
  u16x4 o1 = { f2bf(e[4] * inv), f2bf(e[5] * inv), f2bf(e[6] * inv), f2bf(e[7] * inv) };
  ((u16x4*)prow)[t] = o0;
  ((u16x4*)prow)[256 + t] = o1;
}

// ---------- PV GEMM: out = P @ Vt^T ----------
__global__ __launch_bounds__(256, 2) void pv_kernel(
    const u16* __restrict__ P, const u16* __restrict__ vt, float* __restrict__ out)
{
  const int bx = blockIdx.x, by = blockIdx.y, b = blockIdx.z;
  f32x16 acc[2][2];
  gemm_core_plain(P + ((size_t)b * S_LEN + by * 128) * (2 * S_LEN),
                  vt + ((size_t)b * HDIM + bx * 128) * S_LEN,
                  2 * S_LEN, S_LEN, S_LEN, acc);
  const int lane = threadIdx.x & 63, wave = threadIdx.x >> 6;
  const int wm = wave >> 1, wn = wave & 1;
#pragma unroll
  for (int i = 0; i < 2; ++i) {
#pragma unroll
    for (int j = 0; j < 2; ++j) {
#pragma unroll
      for (int r = 0; r < 16; ++r) {
        const int q = by * 128 + wm * 64 + i * 32 + ROW32(r, lane);
        const int h = bx * 128 + wn * 64 + j * 32 + (lane & 31);
        out[((size_t)b * S_LEN + q) * HDIM + h] = acc[i][j][r];
      }
    }
  }
}

extern "C" void kernel_launch(void* const* d_in, const int* in_sizes, int n_in,
                              void* d_out, int out_size, void* d_ws, size_t ws_size,
                              hipStream_t stream)
{
  const float* qkv  = (const float*)d_in[0];
  const void*  mask = d_in[1];
  const float* W    = (const float*)d_in[2];
  const float* bias = (const float*)d_in[3];
  float* out = (float*)d_out;
  char* ws = (char*)d_ws;

  const size_t off_mask = 0;
  const size_t off_Whi  = 32768;
  const size_t off_Wlo  = off_Whi + (size_t)N3H * DIN * 2;
  const size_t off_Qhi  = off_Wlo + (size_t)N3H * DIN * 2;
  const size_t off_Qlo  = off_Qhi + (size_t)NTOK * HDIM * 2;
  const size_t off_Khi  = off_Qlo + (size_t)NTOK * HDIM * 2;
  const size_t off_Klo  = off_Khi + (size_t)NTOK * HDIM * 2;
  const size_t off_Vt   = off_Klo + (size_t)NTOK * HDIM * 2;
  const size_t off_A    = off_Vt + (size_t)NTOK * HDIM * 2;
  const size_t off_Alo  = off_A + (size_t)NTOK * DIN * 2;
  const size_t off_sc   = off_A;  // scores (67MB) overlay A-split (dead after proj)
  // total ws requirement: off_A + BATCH*S*S*4 = ~156 MiB

  float* maskbias = (float*)(ws + off_mask);
  u16* Whi = (u16*)(ws + off_Whi);  u16* Wlo = (u16*)(ws + off_Wlo);
  u16* Qhi = (u16*)(ws + off_Qhi);  u16* Qlo = (u16*)(ws + off_Qlo);
  u16* Khi = (u16*)(ws + off_Khi);  u16* Klo = (u16*)(ws + off_Klo);
  u16* Vt  = (u16*)(ws + off_Vt);
  u16* Ahi = (u16*)(ws + off_A);    u16* Alo = (u16*)(ws + off_Alo);
  float* scores = (float*)(ws + off_sc);

  prep_mask_kernel<<<1, 256, 0, stream>>>((const unsigned char*)mask, maskbias);
  split_f32_kernel<<<NTOK * DIN / 1024, 256, 0, stream>>>(qkv, Ahi, Alo);
  splitWT_kernel<<<N3H * DIN / 256, 256, 0, stream>>>(W, Whi, Wlo);
  proj_qk_kernel<<<dim3(2 * HDIM / 128, NTOK / 128, 1), 256, 0, stream>>>(
      Ahi, Alo, Whi, Wlo, bias, Qhi, Qlo, Khi, Klo);
  proj_v_kernel<<<dim3(HDIM / 128, NTOK / 128, 1), 256, 0, stream>>>(
      Ahi, Whi, bias, Vt);
  scores_kernel<<<dim3(S_LEN / 128, S_LEN / 128, BATCH), 256, 0, stream>>>(
      Qhi, Qlo, Khi, Klo, maskbias, scores);
  softmax_kernel<<<NTOK, 256, 0, stream>>>(scores);
  pv_kernel<<<dim3(HDIM / 128, S_LEN / 128, BATCH), 256, 0, stream>>>(
      (const u16*)scores, Vt, out);
}

// Round 8
// 405.584 us; speedup vs baseline: 1.1607x; 1.0961x over previous
//
#include <hip/hip_runtime.h>
#include <stdint.h>

// Problem: B=4, S=2048, D_IN=1024, H=1024; fp32 in/out.
// Pipeline: [prep_mask] [split qkv->bf16 hi/lo] [split+transpose W (LDS tile)]
//           [proj_qk GEMM split-bf16 -> Qhi/Qlo/Khi/Klo]
//           [proj_v GEMM plain bf16 -> Vt]
//           [scores GEMM split-bf16 *32 + maskbias -> fp32 scores]
//           [softmax per-wave in-place -> bf16 P]   [PV GEMM bf16 -> out]
// R3: GEMM __launch_bounds__ stays (256,2) — 4 blocks/CU blows per-XCD L2.
// R6: 32x32x16 MFMA + XOR swizzle -> conflicts at the uniform floor (8.4M).
// R7: BK=64 halves barrier count: proj_qk 123->112us (~920 TF raw).
// R8: aux kernels — coalesced splitWT (LDS transpose), barrier-free per-wave
//     softmax with __expf. GEMM cores untouched.

#define S_LEN 2048
#define BATCH 4
#define DIN   1024
#define HDIM  1024
#define N3H   3072
#define NTOK  8192   // BATCH*S_LEN

typedef unsigned short u16;
typedef __attribute__((ext_vector_type(8))) short bf16x8;
typedef __attribute__((ext_vector_type(4))) float f32x4;
typedef __attribute__((ext_vector_type(16))) float f32x16;
typedef __attribute__((ext_vector_type(4))) unsigned short u16x4;

// ---------- bf16 helpers (bit ops, RN) ----------
__device__ __forceinline__ u16 f2bf(float x) {
  union { float f; unsigned u; } c; c.f = x;
  unsigned r = c.u + 0x7fffu + ((c.u >> 16) & 1u);
  return (u16)(r >> 16);
}
__device__ __forceinline__ float bf2f(u16 h) {
  union { unsigned u; float f; } c; c.u = ((unsigned)h) << 16;
  return c.f;
}

// ---------- async global->LDS, width 16 ----------
__device__ __forceinline__ void gload16(const void* g, void* lds) {
  auto* gp = reinterpret_cast<const __attribute__((address_space(1))) void*>(
      reinterpret_cast<uintptr_t>(g));
  auto* lp = reinterpret_cast<__attribute__((address_space(3))) void*>(
      (unsigned)reinterpret_cast<uintptr_t>(lds));
  __builtin_amdgcn_global_load_lds(gp, lp, 16, 0, 0);
}

// Stage a 128x64 bf16 tile (row-major, row stride ld elems) into swizzled LDS.
// Layout: element (row, kb=k/8) at byte row*128 + ((kb ^ (row&7))*16).
// 16 instrs of 1KB (4 waves x 4); instr i = rows i*8..i*8+7. Lane l covers
// (row=i*8+(l>>3), slot=l&7) -> logical kb = (l&7)^((l>>3)&7). Each 8-lane
// group reads one full 128B row (permuted within it) -> coalescing unchanged.
__device__ __forceinline__ void stage_tile(const u16* __restrict__ g, int ld,
                                           u16* lds, int wave, int lane) {
  const int rlane = lane >> 3;                       // 0..7: row within instr
  const int kb    = (lane & 7) ^ (rlane & 7);        // swizzled k-block
#pragma unroll
  for (int h = 0; h < 4; ++h) {
    const int instr = wave * 4 + h;                  // 0..15
    const u16* gp = g + (size_t)(instr * 8 + rlane) * ld + kb * 8;
    gload16(gp, (char*)lds + instr * 1024);
  }
}

// 32x32x16 fragment fetch from swizzled [128][64] LDS tile.
// A-operand layout: A[m=lane&31][k=(lane>>5)*8+j] (R5/R6-verified).
// kh in 0..3 selects the 16-wide k-slice; kb = kh*2 + (lane>>5).
__device__ __forceinline__ bf16x8 frag32(const u16* t, int wq, int sub, int kh,
                                         int lane) {
  const int r5   = lane & 31;
  const int row  = wq * 64 + sub * 32 + r5;
  const int slot = (kh * 2 + (lane >> 5)) ^ (r5 & 7);
  return *(const bf16x8*)(t + row * 64 + slot * 8);
}

// ---------- split-precision gemm_bt core: C(128x128) += (Ah+Al)*(Bh+Bl)^T ----------
// 3 MFMA products (hh, hl, lh); lo*lo dropped (2^-18 rel, negligible).
__device__ __forceinline__ void gemm_core_split(
    const u16* __restrict__ Ah, const u16* __restrict__ Al,
    const u16* __restrict__ Bh, const u16* __restrict__ Bl,
    int lda, int ldb, int K, f32x16 acc[2][2])
{
  __shared__ __align__(16) u16 lds[4 * 8192];  // aH | aL | bH | bL, 16KB each
  u16* aH = lds;           u16* aL = lds + 8192;
  u16* bH = lds + 16384;   u16* bL = lds + 24576;
  const int tid  = threadIdx.x;
  const int wave = tid >> 6, lane = tid & 63;
  const int wm = wave >> 1, wn = wave & 1;

#pragma unroll
  for (int i = 0; i < 2; ++i)
#pragma unroll
    for (int j = 0; j < 2; ++j)
#pragma unroll
      for (int r = 0; r < 16; ++r) acc[i][j][r] = 0.f;

  for (int k0 = 0; k0 < K; k0 += 64) {
    stage_tile(Ah + k0, lda, aH, wave, lane);
    stage_tile(Al + k0, lda, aL, wave, lane);
    stage_tile(Bh + k0, ldb, bH, wave, lane);
    stage_tile(Bl + k0, ldb, bL, wave, lane);
    __syncthreads();   // drains vmcnt (global_load_lds) before LDS reads

#pragma unroll
    for (int kh = 0; kh < 4; ++kh) {
      bf16x8 fah[2], fal[2];
#pragma unroll
      for (int i = 0; i < 2; ++i) {
        fah[i] = frag32(aH, wm, i, kh, lane);
        fal[i] = frag32(aL, wm, i, kh, lane);
      }
#pragma unroll
      for (int j = 0; j < 2; ++j) {
        const bf16x8 fbh = frag32(bH, wn, j, kh, lane);
        const bf16x8 fbl = frag32(bL, wn, j, kh, lane);
#pragma unroll
        for (int i = 0; i < 2; ++i) {
          acc[i][j] = __builtin_amdgcn_mfma_f32_32x32x16_bf16(fah[i], fbh, acc[i][j], 0, 0, 0);
          acc[i][j] = __builtin_amdgcn_mfma_f32_32x32x16_bf16(fah[i], fbl, acc[i][j], 0, 0, 0);
          acc[i][j] = __builtin_amdgcn_mfma_f32_32x32x16_bf16(fal[i], fbh, acc[i][j], 0, 0, 0);
        }
      }
    }
    __syncthreads();   // protect LDS before next stage
  }
}

// ---------- plain bf16 gemm_bt core ----------
__device__ __forceinline__ void gemm_core_plain(
    const u16* __restrict__ A, const u16* __restrict__ B,
    int lda, int ldb, int K, f32x16 acc[2][2])
{
  __shared__ __align__(16) u16 lds[2 * 8192];
  u16* aT = lds; u16* bT = lds + 8192;
  const int tid  = threadIdx.x;
  const int wave = tid >> 6, lane = tid & 63;
  const int wm = wave >> 1, wn = wave & 1;

#pragma unroll
  for (int i = 0; i < 2; ++i)
#pragma unroll
    for (int j = 0; j < 2; ++j)
#pragma unroll
      for (int r = 0; r < 16; ++r) acc[i][j][r] = 0.f;

  for (int k0 = 0; k0 < K; k0 += 64) {
    stage_tile(A + k0, lda, aT, wave, lane);
    stage_tile(B + k0, ldb, bT, wave, lane);
    __syncthreads();
#pragma unroll
    for (int kh = 0; kh < 4; ++kh) {
      bf16x8 fa[2];
#pragma unroll
      for (int i = 0; i < 2; ++i) fa[i] = frag32(aT, wm, i, kh, lane);
#pragma unroll
      for (int j = 0; j < 2; ++j) {
        const bf16x8 fb = frag32(bT, wn, j, kh, lane);
#pragma unroll
        for (int i = 0; i < 2; ++i)
          acc[i][j] = __builtin_amdgcn_mfma_f32_32x32x16_bf16(fa[i], fb, acc[i][j], 0, 0, 0);
      }
    }
    __syncthreads();
  }
}

// C/D layout for 32x32 (HW-verified m74/m101):
//   col = lane&31, row = (reg&3) + 8*(reg>>2) + 4*(lane>>5)
#define ROW32(r, lane) (((r) & 3) + 8 * ((r) >> 2) + 4 * ((lane) >> 5))

// ---------- mask prep: detect bool(1B) vs int32(4B) repr, write additive bias ----------
__global__ void prep_mask_kernel(const unsigned char* __restrict__ m,
                                 float* __restrict__ bias) {
  __shared__ int isBool;
  if (threadIdx.x == 0) isBool = 0;
  __syncthreads();
  for (int i = threadIdx.x; i < NTOK; i += 256)
    if ((i & 3) && m[i]) isBool = 1;   // int32 repr of 0/1 has zero bytes at %4!=0
  __syncthreads();
  const int stride = isBool ? 1 : 4;
  const float ninf = -__builtin_inff();
  for (int i = threadIdx.x; i < NTOK; i += 256)
    bias[i] = m[(size_t)i * stride] ? ninf : 0.f;
}

// ---------- split fp32 -> bf16 hi/lo ----------
__global__ __launch_bounds__(256) void split_f32_kernel(
    const float* __restrict__ x, u16* __restrict__ hi, u16* __restrict__ lo) {
  const int i = (blockIdx.x * 256 + threadIdx.x) * 4;
  const f32x4 v = *(const f32x4*)(x + i);
  u16x4 h, l;
#pragma unroll
  for (int c = 0; c < 4; ++c) {
    h[c] = f2bf(v[c]);
    l[c] = f2bf(v[c] - bf2f(h[c]));
  }
  *(u16x4*)(hi + i) = h;
  *(u16x4*)(lo + i) = l;
}

// ---------- transpose + split W (DINxN3H -> N3HxDIN), 32x32 LDS tile ----------
// R8: old version read W[d*3072+n] with d varying per thread — 256 separate
// 64B lines per block. Now: coalesced f32x4 reads, LDS transpose, u16x4 writes.
__global__ __launch_bounds__(256) void splitWT_kernel(
    const float* __restrict__ W, u16* __restrict__ whi, u16* __restrict__ wlo) {
  __shared__ float tile[32][33];
  const int t = threadIdx.x;
  const int n0 = blockIdx.x * 32;   // 96 tiles over N3H
  const int d0 = blockIdx.y * 32;   // 32 tiles over DIN
  const int dr = t >> 3, nc = (t & 7) * 4;
  const f32x4 v = *(const f32x4*)(W + (size_t)(d0 + dr) * N3H + n0 + nc);
#pragma unroll
  for (int c = 0; c < 4; ++c) tile[dr][nc + c] = v[c];
  __syncthreads();
  const int nr = t >> 3, dc = (t & 7) * 4;
  u16x4 h, l;
#pragma unroll
  for (int c = 0; c < 4; ++c) {
    const float x = tile[dc + c][nr];
    h[c] = f2bf(x);
    l[c] = f2bf(x - bf2f(h[c]));
  }
  const size_t o = (size_t)(n0 + nr) * DIN + d0 + dc;
  *(u16x4*)(whi + o) = h;
  *(u16x4*)(wlo + o) = l;
}

// ---------- projection GEMM (Q,K thirds): split precision ----------
__global__ __launch_bounds__(256, 2) void proj_qk_kernel(
    const u16* __restrict__ Ahi, const u16* __restrict__ Alo,
    const u16* __restrict__ Whi, const u16* __restrict__ Wlo,
    const float* __restrict__ bias,
    u16* __restrict__ qhi, u16* __restrict__ qlo,
    u16* __restrict__ khi, u16* __restrict__ klo)
{
  const int bx = blockIdx.x, by = blockIdx.y;  // bx over 16 tiles (cols 0..2047)
  f32x16 acc[2][2];
  gemm_core_split(Ahi + (size_t)by * 128 * DIN, Alo + (size_t)by * 128 * DIN,
                  Whi + (size_t)bx * 128 * DIN, Wlo + (size_t)bx * 128 * DIN,
                  DIN, DIN, DIN, acc);
  const int lane = threadIdx.x & 63, wave = threadIdx.x >> 6;
  const int wm = wave >> 1, wn = wave & 1;
#pragma unroll
  for (int i = 0; i < 2; ++i) {
#pragma unroll
    for (int j = 0; j < 2; ++j) {
#pragma unroll
      for (int r = 0; r < 16; ++r) {
        const int row = by * 128 + wm * 64 + i * 32 + ROW32(r, lane);  // token
        const int col = bx * 128 + wn * 64 + j * 32 + (lane & 31);     // 0..2047
        const float v = acc[i][j][r] + bias[col];
        const u16 h = f2bf(v);
        const u16 l = f2bf(v - bf2f(h));
        if (col < HDIM) {                       // Q (block-uniform branch)
          const size_t idx = (size_t)row * HDIM + col;
          qhi[idx] = h; qlo[idx] = l;
        } else {                                // K
          const size_t idx = (size_t)row * HDIM + (col - HDIM);
          khi[idx] = h; klo[idx] = l;
        }
      }
    }
  }
}

// ---------- projection GEMM (V third): plain bf16, writes V transposed ----------
__global__ __launch_bounds__(256, 2) void proj_v_kernel(
    const u16* __restrict__ Ahi, const u16* __restrict__ Whi,
    const float* __restrict__ bias, u16* __restrict__ vt)
{
  const int bx = blockIdx.x, by = blockIdx.y;  // bx over 8 tiles (cols 2048..3071)
  f32x16 acc[2][2];
  gemm_core_plain(Ahi + (size_t)by * 128 * DIN,
                  Whi + (size_t)(2048 + bx * 128) * DIN,
                  DIN, DIN, DIN, acc);
  const int lane = threadIdx.x & 63, wave = threadIdx.x >> 6;
  const int wm = wave >> 1, wn = wave & 1;
#pragma unroll
  for (int i = 0; i < 2; ++i) {
#pragma unroll
    for (int j = 0; j < 2; ++j) {
#pragma unroll
      for (int r = 0; r < 16; ++r) {
        const int row = by * 128 + wm * 64 + i * 32 + ROW32(r, lane);  // token
        const int b = row >> 11, s = row & 2047;
        const int hcol = bx * 128 + wn * 64 + j * 32 + (lane & 31);    // 0..1023
        const float v = acc[i][j][r] + bias[2 * HDIM + hcol];
        vt[((size_t)b * HDIM + hcol) * S_LEN + s] = f2bf(v);
      }
    }
  }
}

// ---------- scores GEMM: sc = 32 * Q @ K^T + maskbias(key) ----------
__global__ __launch_bounds__(256, 2) void scores_kernel(
    const u16* __restrict__ qhi, const u16* __restrict__ qlo,
    const u16* __restrict__ khi, const u16* __restrict__ klo,
    const float* __restrict__ maskbias, float* __restrict__ scores)
{
  const int bx = blockIdx.x, by = blockIdx.y, b = blockIdx.z;
  f32x16 acc[2][2];
  const size_t qoff = ((size_t)b * S_LEN + by * 128) * HDIM;
  const size_t koff = ((size_t)b * S_LEN + bx * 128) * HDIM;
  gemm_core_split(qhi + qoff, qlo + qoff, khi + koff, klo + koff,
                  HDIM, HDIM, HDIM, acc);
  const int lane = threadIdx.x & 63, wave = threadIdx.x >> 6;
  const int wm = wave >> 1, wn = wave & 1;
#pragma unroll
  for (int i = 0; i < 2; ++i) {
#pragma unroll
    for (int j = 0; j < 2; ++j) {
#pragma unroll
      for (int r = 0; r < 16; ++r) {
        const int q   = by * 128 + wm * 64 + i * 32 + ROW32(r, lane);
        const int key = bx * 128 + wn * 64 + j * 32 + (lane & 31);
        scores[((size_t)b * S_LEN + q) * S_LEN + key] =
            32.0f * acc[i][j][r] + maskbias[b * S_LEN + key];
      }
    }
  }
}

// ---------- softmax: one wave per row, barrier-free, in-place fp32 -> bf16 ----------
// 4 waves/block, wave w owns row blockIdx*4+w. Lane holds 32 elems (8 x f32x4),
// butterfly __shfl_xor reductions (width 64), __expf.
__global__ __launch_bounds__(256) void softmax_kernel(float* __restrict__ scores) {
  const int wave = threadIdx.x >> 6, lane = threadIdx.x & 63;
  const int row = blockIdx.x * 4 + wave;
  float* srow = scores + (size_t)row * S_LEN;

  f32x4 v[8];
#pragma unroll
  for (int c = 0; c < 8; ++c) v[c] = ((const f32x4*)srow)[c * 64 + lane];

  float m = -__builtin_inff();
#pragma unroll
  for (int c = 0; c < 8; ++c)
    m = fmaxf(m, fmaxf(fmaxf(v[c][0], v[c][1]), fmaxf(v[c][2], v[c][3])));
#pragma unroll
  for (int o = 32; o > 0; o >>= 1) m = fmaxf(m, __shfl_xor(m, o));

  float s = 0.f;
#pragma unroll
  for (int c = 0; c < 8; ++c) {
#pragma unroll
    for (int e = 0; e < 4; ++e) {
      v[c][e] = __expf(v[c][e] - m);
      s += v[c][e];
    }
  }
#pragma unroll
  for (int o = 32; o > 0; o >>= 1) s += __shfl_xor(s, o);
  const float inv = 1.0f / s;

  u16* prow = (u16*)srow;   // bf16 row at same base; valid elems 0..2047, stride 4096
#pragma unroll
  for (int c = 0; c < 8; ++c) {
    u16x4 o4 = { f2bf(v[c][0] * inv), f2bf(v[c][1] * inv),
                 f2bf(v[c][2] * inv), f2bf(v[c][3] * inv) };
    ((u16x4*)prow)[c * 64 + lane] = o4;
  }
}

// ---------- PV GEMM: out = P @ Vt^T ----------
__global__ __launch_bounds__(256, 2) void pv_kernel(
    const u16* __restrict__ P, const u16* __restrict__ vt, float* __restrict__ out)
{
  const int bx = blockIdx.x, by = blockIdx.y, b = blockIdx.z;
  f32x16 acc[2][2];
  gemm_core_plain(P + ((size_t)b * S_LEN + by * 128) * (2 * S_LEN),
                  vt + ((size_t)b * HDIM + bx * 128) * S_LEN,
                  2 * S_LEN, S_LEN, S_LEN, acc);
  const int lane = threadIdx.x & 63, wave = threadIdx.x >> 6;
  const int wm = wave >> 1, wn = wave & 1;
#pragma unroll
  for (int i = 0; i < 2; ++i) {
#pragma unroll
    for (int j = 0; j < 2; ++j) {
#pragma unroll
      for (int r = 0; r < 16; ++r) {
        const int q = by * 128 + wm * 64 + i * 32 + ROW32(r, lane);
        const int h = bx * 128 + wn * 64 + j * 32 + (lane & 31);
        out[((size_t)b * S_LEN + q) * HDIM + h] = acc[i][j][r];
      }
    }
  }
}

extern "C" void kernel_launch(void* const* d_in, const int* in_sizes, int n_in,
                              void* d_out, int out_size, void* d_ws, size_t ws_size,
                              hipStream_t stream)
{
  const float* qkv  = (const float*)d_in[0];
  const void*  mask = d_in[1];
  const float* W    = (const float*)d_in[2];
  const float* bias = (const float*)d_in[3];
  float* out = (float*)d_out;
  char* ws = (char*)d_ws;

  const size_t off_mask = 0;
  const size_t off_Whi  = 32768;
  const size_t off_Wlo  = off_Whi + (size_t)N3H * DIN * 2;
  const size_t off_Qhi  = off_Wlo + (size_t)N3H * DIN * 2;
  const size_t off_Qlo  = off_Qhi + (size_t)NTOK * HDIM * 2;
  const size_t off_Khi  = off_Qlo + (size_t)NTOK * HDIM * 2;
  const size_t off_Klo  = off_Khi + (size_t)NTOK * HDIM * 2;
  const size_t off_Vt   = off_Klo + (size_t)NTOK * HDIM * 2;
  const size_t off_A    = off_Vt + (size_t)NTOK * HDIM * 2;
  const size_t off_Alo  = off_A + (size_t)NTOK * DIN * 2;
  const size_t off_sc   = off_A;  // scores (67MB) overlay A-split (dead after proj)
  // total ws requirement: off_A + BATCH*S*S*4 = ~156 MiB

  float* maskbias = (float*)(ws + off_mask);
  u16* Whi = (u16*)(ws + off_Whi);  u16* Wlo = (u16*)(ws + off_Wlo);
  u16* Qhi = (u16*)(ws + off_Qhi);  u16* Qlo = (u16*)(ws + off_Qlo);
  u16* Khi = (u16*)(ws + off_Khi);  u16* Klo = (u16*)(ws + off_Klo);
  u16* Vt  = (u16*)(ws + off_Vt);
  u16* Ahi = (u16*)(ws + off_A);    u16* Alo = (u16*)(ws + off_Alo);
  float* scores = (float*)(ws + off_sc);

  prep_mask_kernel<<<1, 256, 0, stream>>>((const unsigned char*)mask, maskbias);
  split_f32_kernel<<<NTOK * DIN / 1024, 256, 0, stream>>>(qkv, Ahi, Alo);
  splitWT_kernel<<<dim3(N3H / 32, DIN / 32), 256, 0, stream>>>(W, Whi, Wlo);
  proj_qk_kernel<<<dim3(2 * HDIM / 128, NTOK / 128, 1), 256, 0, stream>>>(
      Ahi, Alo, Whi, Wlo, bias, Qhi, Qlo, Khi, Klo);
  proj_v_kernel<<<dim3(HDIM / 128, NTOK / 128, 1), 256, 0, stream>>>(
      Ahi, Whi, bias, Vt);
  scores_kernel<<<dim3(S_LEN / 128, S_LEN / 128, BATCH), 256, 0, stream>>>(
      Qhi, Qlo, Khi, Klo, maskbias, scores);
  softmax_kernel<<<NTOK / 4, 256, 0, stream>>>(scores);
  pv_kernel<<<dim3(HDIM / 128, S_LEN / 128, BATCH), 256, 0, stream>>>(
      (const u16*)scores, Vt, out);
}

// Round 9
// 402.946 us; speedup vs baseline: 1.1683x; 1.0065x over previous
//
#include <hip/hip_runtime.h>
#include <stdint.h>

// Problem: B=4, S=2048, D_IN=1024, H=1024; fp32 in/out.
// Pipeline: [prep_mask] [split qkv->bf16 hi/lo] [split+transpose W (LDS tile)]
//           [proj_qk GEMM split-bf16 -> Qhi/Qlo/Khi/Klo]
//           [proj_v GEMM plain bf16 -> Vt]
//           [scores GEMM split-bf16 *32 + maskbias -> fp32 scores]
//           [softmax per-wave in-place -> bf16 P]   [PV GEMM bf16 -> out]
// R3: GEMM __launch_bounds__ stays (256,2) — 4 blocks/CU blows per-XCD L2.
// R6: 32x32x16 MFMA + XOR swizzle -> conflicts at the uniform floor (8.4M).
// R7: BK=64 halves barrier count: proj_qk 123->112us (~920 TF raw, the
//     m97-lineage plateau: MFMA floor 41us = LDS floor 41us, 40% util).
// R8: coalesced splitWT + per-wave softmax: 444->405us.
// R9: XCD-aware super-tile swizzle for scores/pv (K/Vt stripes L2-pinned per
//     XCD, 4x4 regions = 4MB working set). Pure block reordering.

#define S_LEN 2048
#define BATCH 4
#define DIN   1024
#define HDIM  1024
#define N3H   3072
#define NTOK  8192   // BATCH*S_LEN

typedef unsigned short u16;
typedef __attribute__((ext_vector_type(8))) short bf16x8;
typedef __attribute__((ext_vector_type(4))) float f32x4;
typedef __attribute__((ext_vector_type(16))) float f32x16;
typedef __attribute__((ext_vector_type(4))) unsigned short u16x4;

// ---------- bf16 helpers (bit ops, RN) ----------
__device__ __forceinline__ u16 f2bf(float x) {
  union { float f; unsigned u; } c; c.f = x;
  unsigned r = c.u + 0x7fffu + ((c.u >> 16) & 1u);
  return (u16)(r >> 16);
}
__device__ __forceinline__ float bf2f(u16 h) {
  union { unsigned u; float f; } c; c.u = ((unsigned)h) << 16;
  return c.f;
}

// ---------- async global->LDS, width 16 ----------
__device__ __forceinline__ void gload16(const void* g, void* lds) {
  auto* gp = reinterpret_cast<const __attribute__((address_space(1))) void*>(
      reinterpret_cast<uintptr_t>(g));
  auto* lp = reinterpret_cast<__attribute__((address_space(3))) void*>(
      (unsigned)reinterpret_cast<uintptr_t>(lds));
  __builtin_amdgcn_global_load_lds(gp, lp, 16, 0, 0);
}

// Stage a 128x64 bf16 tile (row-major, row stride ld elems) into swizzled LDS.
// Layout: element (row, kb=k/8) at byte row*128 + ((kb ^ (row&7))*16).
__device__ __forceinline__ void stage_tile(const u16* __restrict__ g, int ld,
                                           u16* lds, int wave, int lane) {
  const int rlane = lane >> 3;                       // 0..7: row within instr
  const int kb    = (lane & 7) ^ (rlane & 7);        // swizzled k-block
#pragma unroll
  for (int h = 0; h < 4; ++h) {
    const int instr = wave * 4 + h;                  // 0..15
    const u16* gp = g + (size_t)(instr * 8 + rlane) * ld + kb * 8;
    gload16(gp, (char*)lds + instr * 1024);
  }
}

// 32x32x16 fragment fetch from swizzled [128][64] LDS tile.
// A-operand layout: A[m=lane&31][k=(lane>>5)*8+j] (R5/R6-verified).
__device__ __forceinline__ bf16x8 frag32(const u16* t, int wq, int sub, int kh,
                                         int lane) {
  const int r5   = lane & 31;
  const int row  = wq * 64 + sub * 32 + r5;
  const int slot = (kh * 2 + (lane >> 5)) ^ (r5 & 7);
  return *(const bf16x8*)(t + row * 64 + slot * 8);
}

// ---------- split-precision gemm_bt core: C(128x128) += (Ah+Al)*(Bh+Bl)^T ----------
__device__ __forceinline__ void gemm_core_split(
    const u16* __restrict__ Ah, const u16* __restrict__ Al,
    const u16* __restrict__ Bh, const u16* __restrict__ Bl,
    int lda, int ldb, int K, f32x16 acc[2][2])
{
  __shared__ __align__(16) u16 lds[4 * 8192];  // aH | aL | bH | bL, 16KB each
  u16* aH = lds;           u16* aL = lds + 8192;
  u16* bH = lds + 16384;   u16* bL = lds + 24576;
  const int tid  = threadIdx.x;
  const int wave = tid >> 6, lane = tid & 63;
  const int wm = wave >> 1, wn = wave & 1;

#pragma unroll
  for (int i = 0; i < 2; ++i)
#pragma unroll
    for (int j = 0; j < 2; ++j)
#pragma unroll
      for (int r = 0; r < 16; ++r) acc[i][j][r] = 0.f;

  for (int k0 = 0; k0 < K; k0 += 64) {
    stage_tile(Ah + k0, lda, aH, wave, lane);
    stage_tile(Al + k0, lda, aL, wave, lane);
    stage_tile(Bh + k0, ldb, bH, wave, lane);
    stage_tile(Bl + k0, ldb, bL, wave, lane);
    __syncthreads();   // drains vmcnt (global_load_lds) before LDS reads

#pragma unroll
    for (int kh = 0; kh < 4; ++kh) {
      bf16x8 fah[2], fal[2];
#pragma unroll
      for (int i = 0; i < 2; ++i) {
        fah[i] = frag32(aH, wm, i, kh, lane);
        fal[i] = frag32(aL, wm, i, kh, lane);
      }
#pragma unroll
      for (int j = 0; j < 2; ++j) {
        const bf16x8 fbh = frag32(bH, wn, j, kh, lane);
        const bf16x8 fbl = frag32(bL, wn, j, kh, lane);
#pragma unroll
        for (int i = 0; i < 2; ++i) {
          acc[i][j] = __builtin_amdgcn_mfma_f32_32x32x16_bf16(fah[i], fbh, acc[i][j], 0, 0, 0);
          acc[i][j] = __builtin_amdgcn_mfma_f32_32x32x16_bf16(fah[i], fbl, acc[i][j], 0, 0, 0);
          acc[i][j] = __builtin_amdgcn_mfma_f32_32x32x16_bf16(fal[i], fbh, acc[i][j], 0, 0, 0);
        }
      }
    }
    __syncthreads();   // protect LDS before next stage
  }
}

// ---------- plain bf16 gemm_bt core ----------
__device__ __forceinline__ void gemm_core_plain(
    const u16* __restrict__ A, const u16* __restrict__ B,
    int lda, int ldb, int K, f32x16 acc[2][2])
{
  __shared__ __align__(16) u16 lds[2 * 8192];
  u16* aT = lds; u16* bT = lds + 8192;
  const int tid  = threadIdx.x;
  const int wave = tid >> 6, lane = tid & 63;
  const int wm = wave >> 1, wn = wave & 1;

#pragma unroll
  for (int i = 0; i < 2; ++i)
#pragma unroll
    for (int j = 0; j < 2; ++j)
#pragma unroll
      for (int r = 0; r < 16; ++r) acc[i][j][r] = 0.f;

  for (int k0 = 0; k0 < K; k0 += 64) {
    stage_tile(A + k0, lda, aT, wave, lane);
    stage_tile(B + k0, ldb, bT, wave, lane);
    __syncthreads();
#pragma unroll
    for (int kh = 0; kh < 4; ++kh) {
      bf16x8 fa[2];
#pragma unroll
      for (int i = 0; i < 2; ++i) fa[i] = frag32(aT, wm, i, kh, lane);
#pragma unroll
      for (int j = 0; j < 2; ++j) {
        const bf16x8 fb = frag32(bT, wn, j, kh, lane);
#pragma unroll
        for (int i = 0; i < 2; ++i)
          acc[i][j] = __builtin_amdgcn_mfma_f32_32x32x16_bf16(fa[i], fb, acc[i][j], 0, 0, 0);
      }
    }
    __syncthreads();
  }
}

// C/D layout for 32x32 (HW-verified m74/m101):
//   col = lane&31, row = (reg&3) + 8*(reg>>2) + 4*(lane>>5)
#define ROW32(r, lane) (((r) & 3) + 8 * ((r) >> 2) + 4 * ((lane) >> 5))

// ---------- mask prep: detect bool(1B) vs int32(4B) repr, write additive bias ----------
__global__ void prep_mask_kernel(const unsigned char* __restrict__ m,
                                 float* __restrict__ bias) {
  __shared__ int isBool;
  if (threadIdx.x == 0) isBool = 0;
  __syncthreads();
  for (int i = threadIdx.x; i < NTOK; i += 256)
    if ((i & 3) && m[i]) isBool = 1;   // int32 repr of 0/1 has zero bytes at %4!=0
  __syncthreads();
  const int stride = isBool ? 1 : 4;
  const float ninf = -__builtin_inff();
  for (int i = threadIdx.x; i < NTOK; i += 256)
    bias[i] = m[(size_t)i * stride] ? ninf : 0.f;
}

// ---------- split fp32 -> bf16 hi/lo ----------
__global__ __launch_bounds__(256) void split_f32_kernel(
    const float* __restrict__ x, u16* __restrict__ hi, u16* __restrict__ lo) {
  const int i = (blockIdx.x * 256 + threadIdx.x) * 4;
  const f32x4 v = *(const f32x4*)(x + i);
  u16x4 h, l;
#pragma unroll
  for (int c = 0; c < 4; ++c) {
    h[c] = f2bf(v[c]);
    l[c] = f2bf(v[c] - bf2f(h[c]));
  }
  *(u16x4*)(hi + i) = h;
  *(u16x4*)(lo + i) = l;
}

// ---------- transpose + split W (DINxN3H -> N3HxDIN), 32x32 LDS tile ----------
__global__ __launch_bounds__(256) void splitWT_kernel(
    const float* __restrict__ W, u16* __restrict__ whi, u16* __restrict__ wlo) {
  __shared__ float tile[32][33];
  const int t = threadIdx.x;
  const int n0 = blockIdx.x * 32;   // 96 tiles over N3H
  const int d0 = blockIdx.y * 32;   // 32 tiles over DIN
  const int dr = t >> 3, nc = (t & 7) * 4;
  const f32x4 v = *(const f32x4*)(W + (size_t)(d0 + dr) * N3H + n0 + nc);
#pragma unroll
  for (int c = 0; c < 4; ++c) tile[dr][nc + c] = v[c];
  __syncthreads();
  const int nr = t >> 3, dc = (t & 7) * 4;
  u16x4 h, l;
#pragma unroll
  for (int c = 0; c < 4; ++c) {
    const float x = tile[dc + c][nr];
    h[c] = f2bf(x);
    l[c] = f2bf(x - bf2f(h[c]));
  }
  const size_t o = (size_t)(n0 + nr) * DIN + d0 + dc;
  *(u16x4*)(whi + o) = h;
  *(u16x4*)(wlo + o) = l;
}

// ---------- projection GEMM (Q,K thirds): split precision ----------
__global__ __launch_bounds__(256, 2) void proj_qk_kernel(
    const u16* __restrict__ Ahi, const u16* __restrict__ Alo,
    const u16* __restrict__ Whi, const u16* __restrict__ Wlo,
    const float* __restrict__ bias,
    u16* __restrict__ qhi, u16* __restrict__ qlo,
    u16* __restrict__ khi, u16* __restrict__ klo)
{
  const int bx = blockIdx.x, by = blockIdx.y;  // bx over 16 tiles (cols 0..2047)
  f32x16 acc[2][2];
  gemm_core_split(Ahi + (size_t)by * 128 * DIN, Alo + (size_t)by * 128 * DIN,
                  Whi + (size_t)bx * 128 * DIN, Wlo + (size_t)bx * 128 * DIN,
                  DIN, DIN, DIN, acc);
  const int lane = threadIdx.x & 63, wave = threadIdx.x >> 6;
  const int wm = wave >> 1, wn = wave & 1;
#pragma unroll
  for (int i = 0; i < 2; ++i) {
#pragma unroll
    for (int j = 0; j < 2; ++j) {
#pragma unroll
      for (int r = 0; r < 16; ++r) {
        const int row = by * 128 + wm * 64 + i * 32 + ROW32(r, lane);  // token
        const int col = bx * 128 + wn * 64 + j * 32 + (lane & 31);     // 0..2047
        const float v = acc[i][j][r] + bias[col];
        const u16 h = f2bf(v);
        const u16 l = f2bf(v - bf2f(h));
        if (col < HDIM) {                       // Q (block-uniform branch)
          const size_t idx = (size_t)row * HDIM + col;
          qhi[idx] = h; qlo[idx] = l;
        } else {                                // K
          const size_t idx = (size_t)row * HDIM + (col - HDIM);
          khi[idx] = h; klo[idx] = l;
        }
      }
    }
  }
}

// ---------- projection GEMM (V third): plain bf16, writes V transposed ----------
__global__ __launch_bounds__(256, 2) void proj_v_kernel(
    const u16* __restrict__ Ahi, const u16* __restrict__ Whi,
    const float* __restrict__ bias, u16* __restrict__ vt)
{
  const int bx = blockIdx.x, by = blockIdx.y;  // bx over 8 tiles (cols 2048..3071)
  f32x16 acc[2][2];
  gemm_core_plain(Ahi + (size_t)by * 128 * DIN,
                  Whi + (size_t)(2048 + bx * 128) * DIN,
                  DIN, DIN, DIN, acc);
  const int lane = threadIdx.x & 63, wave = threadIdx.x >> 6;
  const int wm = wave >> 1, wn = wave & 1;
#pragma unroll
  for (int i = 0; i < 2; ++i) {
#pragma unroll
    for (int j = 0; j < 2; ++j) {
#pragma unroll
      for (int r = 0; r < 16; ++r) {
        const int row = by * 128 + wm * 64 + i * 32 + ROW32(r, lane);  // token
        const int b = row >> 11, s = row & 2047;
        const int hcol = bx * 128 + wn * 64 + j * 32 + (lane & 31);    // 0..1023
        const float v = acc[i][j][r] + bias[2 * HDIM + hcol];
        vt[((size_t)b * HDIM + hcol) * S_LEN + s] = f2bf(v);
      }
    }
  }
}

// ---------- scores GEMM: sc = 32 * Q @ K^T + maskbias(key) ----------
// R9: flat grid 1024, XCD-aware decode. Assuming block->XCD = id&7:
// each XCD keeps a fixed 4-stripe K column L2-pinned (2MB) and walks two
// 4x4 regions x 4 batches; concurrent working set ~4MB <= per-XCD L2.
__global__ __launch_bounds__(256, 2) void scores_kernel(
    const u16* __restrict__ qhi, const u16* __restrict__ qlo,
    const u16* __restrict__ khi, const u16* __restrict__ klo,
    const float* __restrict__ maskbias, float* __restrict__ scores)
{
  const int id   = blockIdx.x;          // 0..1023
  const int xcd  = id & 7;
  const int s    = id >> 3;             // 0..127
  const int b    = s >> 5;              // batch 0..3
  const int slot = s & 31;
  const int r    = xcd + 8 * (slot >> 4);  // region 0..15
  const int w    = slot & 15;
  const int bx   = (r & 3) * 4 + (w & 3);   // K-tile 0..15 (rX fixed per XCD)
  const int by   = (r >> 2) * 4 + (w >> 2); // Q-tile 0..15

  f32x16 acc[2][2];
  const size_t qoff = ((size_t)b * S_LEN + by * 128) * HDIM;
  const size_t koff = ((size_t)b * S_LEN + bx * 128) * HDIM;
  gemm_core_split(qhi + qoff, qlo + qoff, khi + koff, klo + koff,
                  HDIM, HDIM, HDIM, acc);
  const int lane = threadIdx.x & 63, wave = threadIdx.x >> 6;
  const int wm = wave >> 1, wn = wave & 1;
#pragma unroll
  for (int i = 0; i < 2; ++i) {
#pragma unroll
    for (int j = 0; j < 2; ++j) {
#pragma unroll
      for (int rr = 0; rr < 16; ++rr) {
        const int q   = by * 128 + wm * 64 + i * 32 + ROW32(rr, lane);
        const int key = bx * 128 + wn * 64 + j * 32 + (lane & 31);
        scores[((size_t)b * S_LEN + q) * S_LEN + key] =
            32.0f * acc[i][j][rr] + maskbias[b * S_LEN + key];
      }
    }
  }
}

// ---------- softmax: one wave per row, barrier-free, in-place fp32 -> bf16 ----------
__global__ __launch_bounds__(256) void softmax_kernel(float* __restrict__ scores) {
  const int wave = threadIdx.x >> 6, lane = threadIdx.x & 63;
  const int row = blockIdx.x * 4 + wave;
  float* srow = scores + (size_t)row * S_LEN;

  f32x4 v[8];
#pragma unroll
  for (int c = 0; c < 8; ++c) v[c] = ((const f32x4*)srow)[c * 64 + lane];

  float m = -__builtin_inff();
#pragma unroll
  for (int c = 0; c < 8; ++c)
    m = fmaxf(m, fmaxf(fmaxf(v[c][0], v[c][1]), fmaxf(v[c][2], v[c][3])));
#pragma unroll
  for (int o = 32; o > 0; o >>= 1) m = fmaxf(m, __shfl_xor(m, o));

  float s = 0.f;
#pragma unroll
  for (int c = 0; c < 8; ++c) {
#pragma unroll
    for (int e = 0; e < 4; ++e) {
      v[c][e] = __expf(v[c][e] - m);
      s += v[c][e];
    }
  }
#pragma unroll
  for (int o = 32; o > 0; o >>= 1) s += __shfl_xor(s, o);
  const float inv = 1.0f / s;

  u16* prow = (u16*)srow;   // bf16 row at same base; valid elems 0..2047, stride 4096
#pragma unroll
  for (int c = 0; c < 8; ++c) {
    u16x4 o4 = { f2bf(v[c][0] * inv), f2bf(v[c][1] * inv),
                 f2bf(v[c][2] * inv), f2bf(v[c][3] * inv) };
    ((u16x4*)prow)[c * 64 + lane] = o4;
  }
}

// ---------- PV GEMM: out = P @ Vt^T ----------
// R9: flat grid 512, XCD-aware decode: region r = xcd (2x4 regions of 4x4
// per batch), Vt stripes pinned per XCD.
__global__ __launch_bounds__(256, 2) void pv_kernel(
    const u16* __restrict__ P, const u16* __restrict__ vt, float* __restrict__ out)
{
  const int id   = blockIdx.x;          // 0..511
  const int xcd  = id & 7;
  const int s    = id >> 3;             // 0..63
  const int b    = s >> 4;              // batch 0..3
  const int slot = s & 15;
  const int bx   = (xcd & 1) * 4 + (slot & 3);   // H-tile 0..7
  const int by   = (xcd >> 1) * 4 + (slot >> 2); // Q-tile 0..15

  f32x16 acc[2][2];
  gemm_core_plain(P + ((size_t)b * S_LEN + by * 128) * (2 * S_LEN),
                  vt + ((size_t)b * HDIM + bx * 128) * S_LEN,
                  2 * S_LEN, S_LEN, S_LEN, acc);
  const int lane = threadIdx.x & 63, wave = threadIdx.x >> 6;
  const int wm = wave >> 1, wn = wave & 1;
#pragma unroll
  for (int i = 0; i < 2; ++i) {
#pragma unroll
    for (int j = 0; j < 2; ++j) {
#pragma unroll
      for (int r = 0; r < 16; ++r) {
        const int q = by * 128 + wm * 64 + i * 32 + ROW32(r, lane);
        const int h = bx * 128 + wn * 64 + j * 32 + (lane & 31);
        out[((size_t)b * S_LEN + q) * HDIM + h] = acc[i][j][r];
      }
    }
  }
}

extern "C" void kernel_launch(void* const* d_in, const int* in_sizes, int n_in,
                              void* d_out, int out_size, void* d_ws, size_t ws_size,
                              hipStream_t stream)
{
  const float* qkv  = (const float*)d_in[0];
  const void*  mask = d_in[1];
  const float* W    = (const float*)d_in[2];
  const float* bias = (const float*)d_in[3];
  float* out = (float*)d_out;
  char* ws = (char*)d_ws;

  const size_t off_mask = 0;
  const size_t off_Whi  = 32768;
  const size_t off_Wlo  = off_Whi + (size_t)N3H * DIN * 2;
  const size_t off_Qhi  = off_Wlo + (size_t)N3H * DIN * 2;
  const size_t off_Qlo  = off_Qhi + (size_t)NTOK * HDIM * 2;
  const size_t off_Khi  = off_Qlo + (size_t)NTOK * HDIM * 2;
  const size_t off_Klo  = off_Khi + (size_t)NTOK * HDIM * 2;
  const size_t off_Vt   = off_Klo + (size_t)NTOK * HDIM * 2;
  const size_t off_A    = off_Vt + (size_t)NTOK * HDIM * 2;
  const size_t off_Alo  = off_A + (size_t)NTOK * DIN * 2;
  const size_t off_sc   = off_A;  // scores (67MB) overlay A-split (dead after proj)
  // total ws requirement: off_A + BATCH*S*S*4 = ~156 MiB

  float* maskbias = (float*)(ws + off_mask);
  u16* Whi = (u16*)(ws + off_Whi);  u16* Wlo = (u16*)(ws + off_Wlo);
  u16* Qhi = (u16*)(ws + off_Qhi);  u16* Qlo = (u16*)(ws + off_Qlo);
  u16* Khi = (u16*)(ws + off_Khi);  u16* Klo = (u16*)(ws + off_Klo);
  u16* Vt  = (u16*)(ws + off_Vt);
  u16* Ahi = (u16*)(ws + off_A);    u16* Alo = (u16*)(ws + off_Alo);
  float* scores = (float*)(ws + off_sc);

  prep_mask_kernel<<<1, 256, 0, stream>>>((const unsigned char*)mask, maskbias);
  split_f32_kernel<<<NTOK * DIN / 1024, 256, 0, stream>>>(qkv, Ahi, Alo);
  splitWT_kernel<<<dim3(N3H / 32, DIN / 32), 256, 0, stream>>>(W, Whi, Wlo);
  proj_qk_kernel<<<dim3(2 * HDIM / 128, NTOK / 128, 1), 256, 0, stream>>>(
      Ahi, Alo, Whi, Wlo, bias, Qhi, Qlo, Khi, Klo);
  proj_v_kernel<<<dim3(HDIM / 128, NTOK / 128, 1), 256, 0, stream>>>(
      Ahi, Whi, bias, Vt);
  scores_kernel<<<16 * 16 * BATCH, 256, 0, stream>>>(
      Qhi, Qlo, Khi, Klo, maskbias, scores);
  softmax_kernel<<<NTOK / 4, 256, 0, stream>>>(scores);
  pv_kernel<<<8 * 16 * BATCH, 256, 0, stream>>>(
      (const u16*)scores, Vt, out);
}